// Round 3
// baseline (1124.531 us; speedup 1.0000x reference)
//
#include <hip/hip_runtime.h>
#include <math.h>

#define N_NODES_C 100000
#define N_EDGES_C 3200000
#define NB 782        // ceil(100000 / 128) buckets of 128 nodes
#define BNODES 128
#define LDS_CAP 6144  // per-bucket LDS staging capacity (mean count ~4092)

// ============================ bucketed CSR build ============================

__global__ __launch_bounds__(256) void bucket_hist_kernel(const int* __restrict__ dst,
                                                          int* __restrict__ bcnt, int n_edges) {
    __shared__ int h[NB];
    for (int i = threadIdx.x; i < NB; i += 256) h[i] = 0;
    __syncthreads();
    int base = blockIdx.x * 8192 + threadIdx.x;
#pragma unroll 4
    for (int u = 0; u < 32; ++u) {
        int e = base + u * 256;
        if (e < n_edges) atomicAdd(&h[dst[e] >> 7], 1);
    }
    __syncthreads();
    for (int i = threadIdx.x; i < NB; i += 256) {
        int v = h[i];
        if (v) atomicAdd(&bcnt[i], v);
    }
}

__global__ __launch_bounds__(1024) void bucket_scan_kernel(const int* __restrict__ bcnt,
                                                           int* __restrict__ boffs,
                                                           int* __restrict__ bcur,
                                                           int* __restrict__ offs) {
    __shared__ int s[1024];
    const int tid = threadIdx.x;
    int v = (tid < NB) ? bcnt[tid] : 0;
    s[tid] = v;
    __syncthreads();
    for (int off = 1; off < 1024; off <<= 1) {
        int t = (tid >= off) ? s[tid - off] : 0;
        __syncthreads();
        s[tid] += t;
        __syncthreads();
    }
    if (tid < NB) {
        int ex = s[tid] - v;
        boffs[tid] = ex;
        bcur[tid] = ex;
    }
    if (tid == 0) {
        boffs[NB] = s[1023];
        offs[N_NODES_C] = s[1023];
    }
}

__global__ void bucket_scatter_kernel(const int* __restrict__ src, const int* __restrict__ dst,
                                      int* __restrict__ bcur, unsigned int* __restrict__ stage,
                                      int n_edges) {
    int e = blockIdx.x * blockDim.x + threadIdx.x;
    if (e < n_edges) {
        int d = dst[e];
        int b = d >> 7;
        int pos = atomicAdd(&bcur[b], 1);
        stage[pos] = (unsigned int)src[e] | ((unsigned int)(d & 127) << 17);
    }
}

__global__ __launch_bounds__(256) void bucket_finalize_kernel(const unsigned int* __restrict__ stage,
                                                              const int* __restrict__ boffs,
                                                              int* __restrict__ offs,
                                                              int* __restrict__ srcs) {
    __shared__ int hist[BNODES];
    __shared__ int excl[BNODES];
    __shared__ int curs[BNODES];
    __shared__ int sbuf[LDS_CAP];
    const int b = blockIdx.x, tid = threadIdx.x;
    const int base = boffs[b];
    const int count = boffs[b + 1] - base;
    const int n0 = b * BNODES;
    for (int i = tid; i < BNODES; i += 256) hist[i] = 0;
    __syncthreads();
    for (int i = tid; i < count; i += 256) {
        unsigned int w = stage[base + i];
        atomicAdd(&hist[w >> 17], 1);
    }
    __syncthreads();
    if (tid < BNODES) excl[tid] = hist[tid];
    __syncthreads();
    for (int off = 1; off < BNODES; off <<= 1) {
        int t = 0;
        if (tid < BNODES && tid >= off) t = excl[tid - off];
        __syncthreads();
        if (tid < BNODES) excl[tid] += t;
        __syncthreads();
    }
    if (tid < BNODES) {
        int ex = excl[tid] - hist[tid];  // exclusive prefix
        int n = n0 + tid;
        if (n < N_NODES_C) offs[n] = base + ex;
        curs[tid] = ex;
    }
    __syncthreads();
    if (count <= LDS_CAP) {
        for (int i = tid; i < count; i += 256) {
            unsigned int w = stage[base + i];
            int p = atomicAdd(&curs[w >> 17], 1);
            sbuf[p] = (int)(w & 0x1FFFFu);
        }
        __syncthreads();
        for (int i = tid; i < count; i += 256) srcs[base + i] = sbuf[i];
    } else {  // overflow fallback (never hit for this input)
        for (int i = tid; i < count; i += 256) {
            unsigned int w = stage[base + i];
            int p = atomicAdd(&curs[w >> 17], 1);
            srcs[base + p] = (int)(w & 0x1FFFFu);
        }
    }
}

// ============= gather64: out[n] = relu(feat[n] + sum_{s in adj(n)} feat[s] + bias) =============

__global__ __launch_bounds__(256) void gather64_kernel(const float* __restrict__ feat,
                                                       const int* __restrict__ offs,
                                                       const int* __restrict__ srcs,
                                                       const float* __restrict__ bias,
                                                       float* __restrict__ out, int n_nodes) {
    const int wave = threadIdx.x >> 6;
    const int lane = threadIdx.x & 63;
    const int n = blockIdx.x * 4 + wave;
    if (n >= n_nodes) return;
    float acc = feat[(size_t)n * 64 + lane];
    const int s0 = offs[n], s1 = offs[n + 1];
    int i = s0;
    for (; i + 8 <= s1; i += 8) {
        int sA[8];
#pragma unroll
        for (int u = 0; u < 8; ++u) sA[u] = srcs[i + u];
        float v[8];
#pragma unroll
        for (int u = 0; u < 8; ++u) v[u] = feat[(size_t)sA[u] * 64 + lane];
#pragma unroll
        for (int u = 0; u < 8; ++u) acc += v[u];
    }
    for (; i < s1; ++i) acc += feat[(size_t)srcs[i] * 64 + lane];
    acc = fmaxf(acc + bias[lane], 0.f);
    out[(size_t)n * 64 + lane] = acc;
}

// ============================ dense: out = [relu](in @ W [+ b]), OUT=64 ============================

template <int IN_DIM, bool RELU, bool HAS_BIAS>
__global__ __launch_bounds__(256) void mlp_layer_kernel(const float* __restrict__ in,
                                                        const float* __restrict__ W,
                                                        const float* __restrict__ bias,
                                                        float* __restrict__ out, int n_nodes) {
    __shared__ float sW[IN_DIM * 64];
    __shared__ float sB[64];
    __shared__ float sIn[64][IN_DIM + 4];
    const int tid = threadIdx.x;
    for (int i = tid; i < IN_DIM * 16; i += 256) ((float4*)sW)[i] = ((const float4*)W)[i];
    if (HAS_BIAS) {
        if (tid < 64) sB[tid] = bias[tid];
    }
    const int base = blockIdx.x * 64;
    for (int i = tid; i < 16 * IN_DIM; i += 256) {
        int nl = i / (IN_DIM / 4);
        int k4 = i % (IN_DIM / 4);
        int n = base + nl;
        float4 v = make_float4(0.f, 0.f, 0.f, 0.f);
        if (n < n_nodes) v = ((const float4*)in)[(size_t)n * (IN_DIM / 4) + k4];
        *(float4*)&sIn[nl][k4 * 4] = v;
    }
    __syncthreads();
    const int tj = tid & 15, tn = tid >> 4;
    const int j0 = tj * 4, n0 = tn * 4;
    float acc[4][4];
#pragma unroll
    for (int i = 0; i < 4; ++i)
#pragma unroll
        for (int j = 0; j < 4; ++j) acc[i][j] = HAS_BIAS ? sB[j0 + j] : 0.f;
    for (int k = 0; k < IN_DIM; k += 4) {
        float4 a0 = *(const float4*)&sIn[n0 + 0][k];
        float4 a1 = *(const float4*)&sIn[n0 + 1][k];
        float4 a2 = *(const float4*)&sIn[n0 + 2][k];
        float4 a3 = *(const float4*)&sIn[n0 + 3][k];
        float4 w0 = *(const float4*)&sW[(k + 0) * 64 + j0];
        float4 w1 = *(const float4*)&sW[(k + 1) * 64 + j0];
        float4 w2 = *(const float4*)&sW[(k + 2) * 64 + j0];
        float4 w3 = *(const float4*)&sW[(k + 3) * 64 + j0];
#define GIN_STEP(ai, i)                                                                               \
        acc[i][0] += ai.x * w0.x; acc[i][1] += ai.x * w0.y; acc[i][2] += ai.x * w0.z; acc[i][3] += ai.x * w0.w; \
        acc[i][0] += ai.y * w1.x; acc[i][1] += ai.y * w1.y; acc[i][2] += ai.y * w1.z; acc[i][3] += ai.y * w1.w; \
        acc[i][0] += ai.z * w2.x; acc[i][1] += ai.z * w2.y; acc[i][2] += ai.z * w2.z; acc[i][3] += ai.z * w2.w; \
        acc[i][0] += ai.w * w3.x; acc[i][1] += ai.w * w3.y; acc[i][2] += ai.w * w3.z; acc[i][3] += ai.w * w3.w;
        GIN_STEP(a0, 0) GIN_STEP(a1, 1) GIN_STEP(a2, 2) GIN_STEP(a3, 3)
#undef GIN_STEP
    }
#pragma unroll
    for (int i = 0; i < 4; ++i) {
        int n = base + n0 + i;
        if (n < n_nodes) {
            float4 o;
            o.x = RELU ? fmaxf(acc[i][0], 0.f) : acc[i][0];
            o.y = RELU ? fmaxf(acc[i][1], 0.f) : acc[i][1];
            o.z = RELU ? fmaxf(acc[i][2], 0.f) : acc[i][2];
            o.w = RELU ? fmaxf(acc[i][3], 0.f) : acc[i][3];
            *(float4*)&out[(size_t)n * 64 + j0] = o;
        }
    }
}

// ============================ final: log_softmax(in @ Wf + bf), IN=64, OUT=40 ============================

__global__ __launch_bounds__(256) void final_logsoftmax_kernel(const float* __restrict__ in,
                                                               const float* __restrict__ W,
                                                               const float* __restrict__ bias,
                                                               float* __restrict__ out, int n_nodes) {
    __shared__ float sW[64 * 40];
    __shared__ float sB[40];
    __shared__ float sIn[100][68];
    __shared__ float sLog[100][40];
    const int tid = threadIdx.x;
    for (int i = tid; i < 64 * 10; i += 256) ((float4*)sW)[i] = ((const float4*)W)[i];
    if (tid < 40) sB[tid] = bias[tid];
    const int base = blockIdx.x * 100;
    for (int i = tid; i < 100 * 16; i += 256) {
        int nl = i / 16, k4 = i % 16;
        int n = base + nl;
        float4 v = make_float4(0.f, 0.f, 0.f, 0.f);
        if (n < n_nodes) v = ((const float4*)in)[(size_t)n * 16 + k4];
        *(float4*)&sIn[nl][k4 * 4] = v;
    }
    __syncthreads();
    if (tid < 250) {
        const int tj = tid % 10, tn = tid / 10;
        const int j0 = tj * 4, n0 = tn * 4;
        float acc[4][4];
#pragma unroll
        for (int i = 0; i < 4; ++i)
#pragma unroll
            for (int j = 0; j < 4; ++j) acc[i][j] = sB[j0 + j];
        for (int k = 0; k < 64; k += 4) {
            float4 a0 = *(const float4*)&sIn[n0 + 0][k];
            float4 a1 = *(const float4*)&sIn[n0 + 1][k];
            float4 a2 = *(const float4*)&sIn[n0 + 2][k];
            float4 a3 = *(const float4*)&sIn[n0 + 3][k];
            float4 w0 = *(const float4*)&sW[(k + 0) * 40 + j0];
            float4 w1 = *(const float4*)&sW[(k + 1) * 40 + j0];
            float4 w2 = *(const float4*)&sW[(k + 2) * 40 + j0];
            float4 w3 = *(const float4*)&sW[(k + 3) * 40 + j0];
#define GIN_STEP(ai, i)                                                                               \
            acc[i][0] += ai.x * w0.x; acc[i][1] += ai.x * w0.y; acc[i][2] += ai.x * w0.z; acc[i][3] += ai.x * w0.w; \
            acc[i][0] += ai.y * w1.x; acc[i][1] += ai.y * w1.y; acc[i][2] += ai.y * w1.z; acc[i][3] += ai.y * w1.w; \
            acc[i][0] += ai.z * w2.x; acc[i][1] += ai.z * w2.y; acc[i][2] += ai.z * w2.z; acc[i][3] += ai.z * w2.w; \
            acc[i][0] += ai.w * w3.x; acc[i][1] += ai.w * w3.y; acc[i][2] += ai.w * w3.z; acc[i][3] += ai.w * w3.w;
            GIN_STEP(a0, 0) GIN_STEP(a1, 1) GIN_STEP(a2, 2) GIN_STEP(a3, 3)
#undef GIN_STEP
        }
#pragma unroll
        for (int i = 0; i < 4; ++i)
            *(float4*)&sLog[n0 + i][j0] = make_float4(acc[i][0], acc[i][1], acc[i][2], acc[i][3]);
    }
    __syncthreads();
    for (int nl = tid; nl < 100; nl += 256) {
        int n = base + nl;
        if (n >= n_nodes) continue;
        float m = -1e30f;
        for (int j = 0; j < 40; ++j) m = fmaxf(m, sLog[nl][j]);
        float s = 0.f;
        for (int j = 0; j < 40; ++j) s += expf(sLog[nl][j] - m);
        float lse = m + logf(s);
        for (int j = 0; j < 40; j += 4) {
            float4 o;
            o.x = sLog[nl][j + 0] - lse;
            o.y = sLog[nl][j + 1] - lse;
            o.z = sLog[nl][j + 2] - lse;
            o.w = sLog[nl][j + 3] - lse;
            *(float4*)&out[(size_t)n * 40 + j] = o;
        }
    }
}

// ============================ launch ============================

extern "C" void kernel_launch(void* const* d_in, const int* in_sizes, int n_in,
                              void* d_out, int out_size, void* d_ws, size_t ws_size,
                              hipStream_t stream) {
    const float* x  = (const float*)d_in[0];
    const int*   ei = (const int*)d_in[1];
    const float* W1 = (const float*)d_in[2];
    const float* b1 = (const float*)d_in[3];
    const float* W2 = (const float*)d_in[4];
    const float* b2 = (const float*)d_in[5];
    const float* W3 = (const float*)d_in[6];
    const float* b3 = (const float*)d_in[7];
    const float* W4 = (const float*)d_in[8];
    const float* b4 = (const float*)d_in[9];
    const float* Wf = (const float*)d_in[10];
    const float* bf = (const float*)d_in[11];
    float* outp = (float*)d_out;

    const int N = N_NODES_C, E = N_EDGES_C;
    const int* srcp = ei;
    const int* dstp = ei + E;

    // workspace layout (~103 MB)
    char* ws = (char*)d_ws;
    int*          offs  = (int*)(ws);                    // N+1 ints      [0, 400128)
    int*          bcnt  = (int*)(ws + 400128);           // NB ints       -> 404224
    int*          boffs = (int*)(ws + 404224);           // NB+1 ints     -> 408320
    int*          bcur  = (int*)(ws + 408320);           // NB ints       -> 412416
    unsigned int* stage = (unsigned int*)(ws + 412416);  // E u32         -> 13212416
    int*          srcs  = (int*)(ws + 13212416);         // E ints        -> 26012416
    float*        F1    = (float*)(ws + 26012416);       // N*64 f32      -> 51612416
    float*        F2    = (float*)(ws + 51612416);       // N*64 f32      -> 77212416
    float*        F3    = (float*)(ws + 77212416);       // N*64 f32      -> 102812416

    // ---- bucketed CSR build ----
    hipMemsetAsync(bcnt, 0, 4096, stream);
    bucket_hist_kernel<<<(E + 8191) / 8192, 256, 0, stream>>>(dstp, bcnt, E);
    bucket_scan_kernel<<<1, 1024, 0, stream>>>(bcnt, boffs, bcur, offs);
    bucket_scatter_kernel<<<(E + 255) / 256, 256, 0, stream>>>(srcp, dstp, bcur, stage, E);
    bucket_finalize_kernel<<<NB, 256, 0, stream>>>(stage, boffs, offs, srcs);

    const int mlp_grid = (N + 63) / 64;
    const int gat_grid = (N + 3) / 4;

    // ---- conv1 via linearity: y = x@W1; h1 = relu(y + sum y[src] + b1); c1r = relu(h1@W2+b2) ----
    mlp_layer_kernel<128, false, false><<<mlp_grid, 256, 0, stream>>>(x, W1, nullptr, F1, N);
    gather64_kernel<<<gat_grid, 256, 0, stream>>>(F1, offs, srcs, b1, F2, N);
    mlp_layer_kernel<64, true, true><<<mlp_grid, 256, 0, stream>>>(F2, W2, b2, F3, N);

    // ---- conv2 via linearity ----
    mlp_layer_kernel<64, false, false><<<mlp_grid, 256, 0, stream>>>(F3, W3, nullptr, F1, N);
    gather64_kernel<<<gat_grid, 256, 0, stream>>>(F1, offs, srcs, b3, F2, N);
    mlp_layer_kernel<64, true, true><<<mlp_grid, 256, 0, stream>>>(F2, W4, b4, F3, N);

    // ---- final fc + log_softmax ----
    final_logsoftmax_kernel<<<(N + 99) / 100, 256, 0, stream>>>(F3, Wf, bf, outp, N);
}

// Round 4
// 417.019 us; speedup vs baseline: 2.6966x; 2.6966x over previous
//
#include <hip/hip_runtime.h>
#include <math.h>

#define N_NODES_C 100000
#define N_EDGES_C 3200000
#define NB 782        // ceil(100000 / 128) buckets of 128 nodes
#define BNODES 128
#define LDS_CAP 6144  // per-bucket LDS staging capacity (mean count ~4092, 32 sigma margin)
#define CHUNK 16384   // edges per partition block
#define NBLK 196      // ceil(N_EDGES_C / CHUNK)

// ============================ atomic-free bucketed partition ============================

// pass A: per-chunk histogram of dst>>7, written bucket-major: cnt[bucket*NBLK + blk]
__global__ __launch_bounds__(256) void passA_hist_kernel(const int* __restrict__ dst,
                                                         int* __restrict__ cnt, int n_edges) {
    __shared__ int h[NB];
    for (int i = threadIdx.x; i < NB; i += 256) h[i] = 0;
    __syncthreads();
    const int blk = blockIdx.x;
    const int end = min((blk + 1) * CHUNK, n_edges);
    for (int e = blk * CHUNK + threadIdx.x; e < end; e += 256)
        atomicAdd(&h[dst[e] >> 7], 1);
    __syncthreads();
    for (int i = threadIdx.x; i < NB; i += 256) cnt[i * NBLK + blk] = h[i];
}

// inclusive scan of a[0..n) in chunks of 1024 (256 thr x 4), chunk totals -> bsums
__global__ __launch_bounds__(256) void scan_chunks_kernel(int* __restrict__ a, int n, int* __restrict__ bsums) {
    __shared__ int s[256];
    const int tid = threadIdx.x;
    int base = blockIdx.x * 1024 + tid * 4;
    int v[4];
#pragma unroll
    for (int i = 0; i < 4; ++i) v[i] = (base + i < n) ? a[base + i] : 0;
    int tsum = v[0] + v[1] + v[2] + v[3];
    s[tid] = tsum;
    __syncthreads();
    for (int off = 1; off < 256; off <<= 1) {
        int t = (tid >= off) ? s[tid - off] : 0;
        __syncthreads();
        s[tid] += t;
        __syncthreads();
    }
    int run = s[tid] - tsum;
#pragma unroll
    for (int i = 0; i < 4; ++i) {
        run += v[i];
        if (base + i < n) a[base + i] = run;
    }
    if (tid == 255) bsums[blockIdx.x] = s[255];
}

// exclusive scan of bsums[0..nb), nb <= 256, single block of 256
__global__ __launch_bounds__(256) void scan_sums_kernel(int* __restrict__ bsums, int nb) {
    __shared__ int s[256];
    const int tid = threadIdx.x;
    int v = (tid < nb) ? bsums[tid] : 0;
    s[tid] = v;
    __syncthreads();
    for (int off = 1; off < 256; off <<= 1) {
        int t = (tid >= off) ? s[tid - off] : 0;
        __syncthreads();
        s[tid] += t;
        __syncthreads();
    }
    if (tid < nb) bsums[tid] = s[tid] - v;
}

__global__ __launch_bounds__(256) void scan_add_kernel(int* __restrict__ a, int n, const int* __restrict__ bsums) {
    int base = blockIdx.x * 1024 + threadIdx.x * 4;
    int add = bsums[blockIdx.x];
#pragma unroll
    for (int i = 0; i < 4; ++i)
        if (base + i < n) a[base + i] += add;
}

// boffs[b] = exclusive prefix at bucket boundary; also offs[N] = E
__global__ __launch_bounds__(1024) void boffs_kernel(const int* __restrict__ incl,
                                                     int* __restrict__ boffs,
                                                     int* __restrict__ offs) {
    const int b = threadIdx.x;
    if (b < NB) boffs[b] = b ? incl[b * NBLK - 1] : 0;
    if (b == 0) {
        int total = incl[NB * NBLK - 1];
        boffs[NB] = total;
        offs[N_NODES_C] = total;
    }
}

// pass B: scatter each edge to its reserved (block,bucket) range; rank via LDS atomics
__global__ __launch_bounds__(256) void passB_scatter_kernel(const int* __restrict__ src,
                                                            const int* __restrict__ dst,
                                                            const int* __restrict__ incl,
                                                            unsigned int* __restrict__ stage,
                                                            int n_edges) {
    __shared__ int cur[NB];
    const int blk = blockIdx.x;
    for (int i = threadIdx.x; i < NB; i += 256) {
        int idx = i * NBLK + blk;
        cur[i] = idx ? incl[idx - 1] : 0;
    }
    __syncthreads();
    const int end = min((blk + 1) * CHUNK, n_edges);
    for (int e = blk * CHUNK + threadIdx.x; e < end; e += 256) {
        int d = dst[e];
        int b = d >> 7;
        int pos = atomicAdd(&cur[b], 1);
        stage[pos] = (unsigned int)src[e] | ((unsigned int)(d & 127) << 17);
    }
}

__global__ __launch_bounds__(256) void bucket_finalize_kernel(const unsigned int* __restrict__ stage,
                                                              const int* __restrict__ boffs,
                                                              int* __restrict__ offs,
                                                              int* __restrict__ srcs) {
    __shared__ int hist[BNODES];
    __shared__ int excl[BNODES];
    __shared__ int curs[BNODES];
    __shared__ int sbuf[LDS_CAP];
    const int b = blockIdx.x, tid = threadIdx.x;
    const int base = boffs[b];
    const int count = boffs[b + 1] - base;
    const int n0 = b * BNODES;
    for (int i = tid; i < BNODES; i += 256) hist[i] = 0;
    __syncthreads();
    for (int i = tid; i < count; i += 256) {
        unsigned int w = stage[base + i];
        atomicAdd(&hist[w >> 17], 1);
    }
    __syncthreads();
    if (tid < BNODES) excl[tid] = hist[tid];
    __syncthreads();
    for (int off = 1; off < BNODES; off <<= 1) {
        int t = 0;
        if (tid < BNODES && tid >= off) t = excl[tid - off];
        __syncthreads();
        if (tid < BNODES) excl[tid] += t;
        __syncthreads();
    }
    if (tid < BNODES) {
        int ex = excl[tid] - hist[tid];
        int n = n0 + tid;
        if (n < N_NODES_C) offs[n] = base + ex;
        curs[tid] = ex;
    }
    __syncthreads();
    if (count <= LDS_CAP) {
        for (int i = tid; i < count; i += 256) {
            unsigned int w = stage[base + i];
            int p = atomicAdd(&curs[w >> 17], 1);
            sbuf[p] = (int)(w & 0x1FFFFu);
        }
        __syncthreads();
        for (int i = tid; i < count; i += 256) srcs[base + i] = sbuf[i];
    } else {
        for (int i = tid; i < count; i += 256) {
            unsigned int w = stage[base + i];
            int p = atomicAdd(&curs[w >> 17], 1);
            srcs[base + p] = (int)(w & 0x1FFFFu);
        }
    }
}

// ============= gather64: out[n] = relu(feat[n] + sum_{s in adj(n)} feat[s] + bias) =============

__global__ __launch_bounds__(256) void gather64_kernel(const float* __restrict__ feat,
                                                       const int* __restrict__ offs,
                                                       const int* __restrict__ srcs,
                                                       const float* __restrict__ bias,
                                                       float* __restrict__ out, int n_nodes) {
    const int wave = threadIdx.x >> 6;
    const int lane = threadIdx.x & 63;
    const int n = blockIdx.x * 4 + wave;
    if (n >= n_nodes) return;
    float acc = feat[(size_t)n * 64 + lane];
    const int s0 = offs[n], s1 = offs[n + 1];
    int i = s0;
    for (; i + 8 <= s1; i += 8) {
        int sA[8];
#pragma unroll
        for (int u = 0; u < 8; ++u) sA[u] = srcs[i + u];
        float v[8];
#pragma unroll
        for (int u = 0; u < 8; ++u) v[u] = feat[(size_t)sA[u] * 64 + lane];
#pragma unroll
        for (int u = 0; u < 8; ++u) acc += v[u];
    }
    for (; i < s1; ++i) acc += feat[(size_t)srcs[i] * 64 + lane];
    acc = fmaxf(acc + bias[lane], 0.f);
    out[(size_t)n * 64 + lane] = acc;
}

// ============================ dense: out = [relu](in @ W [+ b]), OUT=64 ============================

template <int IN_DIM, bool RELU, bool HAS_BIAS>
__global__ __launch_bounds__(256) void mlp_layer_kernel(const float* __restrict__ in,
                                                        const float* __restrict__ W,
                                                        const float* __restrict__ bias,
                                                        float* __restrict__ out, int n_nodes) {
    __shared__ float sW[IN_DIM * 64];
    __shared__ float sB[64];
    __shared__ float sIn[64][IN_DIM + 4];
    const int tid = threadIdx.x;
    for (int i = tid; i < IN_DIM * 16; i += 256) ((float4*)sW)[i] = ((const float4*)W)[i];
    if (HAS_BIAS) {
        if (tid < 64) sB[tid] = bias[tid];
    }
    const int base = blockIdx.x * 64;
    for (int i = tid; i < 16 * IN_DIM; i += 256) {
        int nl = i / (IN_DIM / 4);
        int k4 = i % (IN_DIM / 4);
        int n = base + nl;
        float4 v = make_float4(0.f, 0.f, 0.f, 0.f);
        if (n < n_nodes) v = ((const float4*)in)[(size_t)n * (IN_DIM / 4) + k4];
        *(float4*)&sIn[nl][k4 * 4] = v;
    }
    __syncthreads();
    const int tj = tid & 15, tn = tid >> 4;
    const int j0 = tj * 4, n0 = tn * 4;
    float acc[4][4];
#pragma unroll
    for (int i = 0; i < 4; ++i)
#pragma unroll
        for (int j = 0; j < 4; ++j) acc[i][j] = HAS_BIAS ? sB[j0 + j] : 0.f;
    for (int k = 0; k < IN_DIM; k += 4) {
        float4 a0 = *(const float4*)&sIn[n0 + 0][k];
        float4 a1 = *(const float4*)&sIn[n0 + 1][k];
        float4 a2 = *(const float4*)&sIn[n0 + 2][k];
        float4 a3 = *(const float4*)&sIn[n0 + 3][k];
        float4 w0 = *(const float4*)&sW[(k + 0) * 64 + j0];
        float4 w1 = *(const float4*)&sW[(k + 1) * 64 + j0];
        float4 w2 = *(const float4*)&sW[(k + 2) * 64 + j0];
        float4 w3 = *(const float4*)&sW[(k + 3) * 64 + j0];
#define GIN_STEP(ai, i)                                                                               \
        acc[i][0] += ai.x * w0.x; acc[i][1] += ai.x * w0.y; acc[i][2] += ai.x * w0.z; acc[i][3] += ai.x * w0.w; \
        acc[i][0] += ai.y * w1.x; acc[i][1] += ai.y * w1.y; acc[i][2] += ai.y * w1.z; acc[i][3] += ai.y * w1.w; \
        acc[i][0] += ai.z * w2.x; acc[i][1] += ai.z * w2.y; acc[i][2] += ai.z * w2.z; acc[i][3] += ai.z * w2.w; \
        acc[i][0] += ai.w * w3.x; acc[i][1] += ai.w * w3.y; acc[i][2] += ai.w * w3.z; acc[i][3] += ai.w * w3.w;
        GIN_STEP(a0, 0) GIN_STEP(a1, 1) GIN_STEP(a2, 2) GIN_STEP(a3, 3)
#undef GIN_STEP
    }
#pragma unroll
    for (int i = 0; i < 4; ++i) {
        int n = base + n0 + i;
        if (n < n_nodes) {
            float4 o;
            o.x = RELU ? fmaxf(acc[i][0], 0.f) : acc[i][0];
            o.y = RELU ? fmaxf(acc[i][1], 0.f) : acc[i][1];
            o.z = RELU ? fmaxf(acc[i][2], 0.f) : acc[i][2];
            o.w = RELU ? fmaxf(acc[i][3], 0.f) : acc[i][3];
            *(float4*)&out[(size_t)n * 64 + j0] = o;
        }
    }
}

// ============================ final: log_softmax(in @ Wf + bf), IN=64, OUT=40 ============================

__global__ __launch_bounds__(256) void final_logsoftmax_kernel(const float* __restrict__ in,
                                                               const float* __restrict__ W,
                                                               const float* __restrict__ bias,
                                                               float* __restrict__ out, int n_nodes) {
    __shared__ float sW[64 * 40];
    __shared__ float sB[40];
    __shared__ float sIn[100][68];
    __shared__ float sLog[100][40];
    const int tid = threadIdx.x;
    for (int i = tid; i < 64 * 10; i += 256) ((float4*)sW)[i] = ((const float4*)W)[i];
    if (tid < 40) sB[tid] = bias[tid];
    const int base = blockIdx.x * 100;
    for (int i = tid; i < 100 * 16; i += 256) {
        int nl = i / 16, k4 = i % 16;
        int n = base + nl;
        float4 v = make_float4(0.f, 0.f, 0.f, 0.f);
        if (n < n_nodes) v = ((const float4*)in)[(size_t)n * 16 + k4];
        *(float4*)&sIn[nl][k4 * 4] = v;
    }
    __syncthreads();
    if (tid < 250) {
        const int tj = tid % 10, tn = tid / 10;
        const int j0 = tj * 4, n0 = tn * 4;
        float acc[4][4];
#pragma unroll
        for (int i = 0; i < 4; ++i)
#pragma unroll
            for (int j = 0; j < 4; ++j) acc[i][j] = sB[j0 + j];
        for (int k = 0; k < 64; k += 4) {
            float4 a0 = *(const float4*)&sIn[n0 + 0][k];
            float4 a1 = *(const float4*)&sIn[n0 + 1][k];
            float4 a2 = *(const float4*)&sIn[n0 + 2][k];
            float4 a3 = *(const float4*)&sIn[n0 + 3][k];
            float4 w0 = *(const float4*)&sW[(k + 0) * 40 + j0];
            float4 w1 = *(const float4*)&sW[(k + 1) * 40 + j0];
            float4 w2 = *(const float4*)&sW[(k + 2) * 40 + j0];
            float4 w3 = *(const float4*)&sW[(k + 3) * 40 + j0];
#define GIN_STEP(ai, i)                                                                               \
            acc[i][0] += ai.x * w0.x; acc[i][1] += ai.x * w0.y; acc[i][2] += ai.x * w0.z; acc[i][3] += ai.x * w0.w; \
            acc[i][0] += ai.y * w1.x; acc[i][1] += ai.y * w1.y; acc[i][2] += ai.y * w1.z; acc[i][3] += ai.y * w1.w; \
            acc[i][0] += ai.z * w2.x; acc[i][1] += ai.z * w2.y; acc[i][2] += ai.z * w2.z; acc[i][3] += ai.z * w2.w; \
            acc[i][0] += ai.w * w3.x; acc[i][1] += ai.w * w3.y; acc[i][2] += ai.w * w3.z; acc[i][3] += ai.w * w3.w;
            GIN_STEP(a0, 0) GIN_STEP(a1, 1) GIN_STEP(a2, 2) GIN_STEP(a3, 3)
#undef GIN_STEP
        }
#pragma unroll
        for (int i = 0; i < 4; ++i)
            *(float4*)&sLog[n0 + i][j0] = make_float4(acc[i][0], acc[i][1], acc[i][2], acc[i][3]);
    }
    __syncthreads();
    for (int nl = tid; nl < 100; nl += 256) {
        int n = base + nl;
        if (n >= n_nodes) continue;
        float m = -1e30f;
        for (int j = 0; j < 40; ++j) m = fmaxf(m, sLog[nl][j]);
        float s = 0.f;
        for (int j = 0; j < 40; ++j) s += expf(sLog[nl][j] - m);
        float lse = m + logf(s);
        for (int j = 0; j < 40; j += 4) {
            float4 o;
            o.x = sLog[nl][j + 0] - lse;
            o.y = sLog[nl][j + 1] - lse;
            o.z = sLog[nl][j + 2] - lse;
            o.w = sLog[nl][j + 3] - lse;
            *(float4*)&out[(size_t)n * 40 + j] = o;
        }
    }
}

// ============================ launch ============================

extern "C" void kernel_launch(void* const* d_in, const int* in_sizes, int n_in,
                              void* d_out, int out_size, void* d_ws, size_t ws_size,
                              hipStream_t stream) {
    const float* x  = (const float*)d_in[0];
    const int*   ei = (const int*)d_in[1];
    const float* W1 = (const float*)d_in[2];
    const float* b1 = (const float*)d_in[3];
    const float* W2 = (const float*)d_in[4];
    const float* b2 = (const float*)d_in[5];
    const float* W3 = (const float*)d_in[6];
    const float* b3 = (const float*)d_in[7];
    const float* W4 = (const float*)d_in[8];
    const float* b4 = (const float*)d_in[9];
    const float* Wf = (const float*)d_in[10];
    const float* bf = (const float*)d_in[11];
    float* outp = (float*)d_out;

    const int N = N_NODES_C, E = N_EDGES_C;
    const int* srcp = ei;
    const int* dstp = ei + E;

    // workspace layout (~103.5 MB)
    char* ws = (char*)d_ws;
    int*          offs  = (int*)(ws);                    // N+1 ints        -> 400128
    int*          boffs = (int*)(ws + 400128);           // NB+1 ints       -> 404352
    int*          bsums = (int*)(ws + 404352);           // 256 ints        -> 405376
    int*          cnt   = (int*)(ws + 405376);           // NB*NBLK ints    -> 1018624 (613,088 B used)
    unsigned int* stage = (unsigned int*)(ws + 1018624); // E u32           -> 13818624
    int*          srcs  = (int*)(ws + 13818624);         // E ints          -> 26618624
    float*        F1    = (float*)(ws + 26618624);       // N*64 f32        -> 52218624
    float*        F2    = (float*)(ws + 52218624);       // N*64 f32        -> 77818624
    float*        F3    = (float*)(ws + 77818624);       // N*64 f32        -> 103418624

    // ---- atomic-free bucketed CSR build ----
    passA_hist_kernel<<<NBLK, 256, 0, stream>>>(dstp, cnt, E);
    const int n_scan = NB * NBLK;                 // 153,272
    const int nblk_scan = (n_scan + 1023) / 1024; // 150
    scan_chunks_kernel<<<nblk_scan, 256, 0, stream>>>(cnt, n_scan, bsums);
    scan_sums_kernel<<<1, 256, 0, stream>>>(bsums, nblk_scan);
    scan_add_kernel<<<nblk_scan, 256, 0, stream>>>(cnt, n_scan, bsums);
    boffs_kernel<<<1, 1024, 0, stream>>>(cnt, boffs, offs);
    passB_scatter_kernel<<<NBLK, 256, 0, stream>>>(srcp, dstp, cnt, stage, E);
    bucket_finalize_kernel<<<NB, 256, 0, stream>>>(stage, boffs, offs, srcs);

    const int mlp_grid = (N + 63) / 64;
    const int gat_grid = (N + 3) / 4;

    // ---- conv1 via linearity: y = x@W1; h1 = relu(y + sum y[src] + b1); c1r = relu(h1@W2+b2) ----
    mlp_layer_kernel<128, false, false><<<mlp_grid, 256, 0, stream>>>(x, W1, nullptr, F1, N);
    gather64_kernel<<<gat_grid, 256, 0, stream>>>(F1, offs, srcs, b1, F2, N);
    mlp_layer_kernel<64, true, true><<<mlp_grid, 256, 0, stream>>>(F2, W2, b2, F3, N);

    // ---- conv2 via linearity ----
    mlp_layer_kernel<64, false, false><<<mlp_grid, 256, 0, stream>>>(F3, W3, nullptr, F1, N);
    gather64_kernel<<<gat_grid, 256, 0, stream>>>(F1, offs, srcs, b3, F2, N);
    mlp_layer_kernel<64, true, true><<<mlp_grid, 256, 0, stream>>>(F2, W4, b4, F3, N);

    // ---- final fc + log_softmax ----
    final_logsoftmax_kernel<<<(N + 99) / 100, 256, 0, stream>>>(F3, Wf, bf, outp, N);
}

// Round 5
// 394.669 us; speedup vs baseline: 2.8493x; 1.0566x over previous
//
#include <hip/hip_runtime.h>
#include <math.h>

#define N_NODES_C 100000
#define N_EDGES_C 3200000
#define NB 782        // ceil(100000 / 128) buckets of 128 nodes
#define BNODES 128
#define LDS_CAP 6144  // per-bucket LDS staging capacity (mean ~4092, +32 sigma)
#define CHUNK 16384   // edges per partition block
#define NBLK 196      // ceil(N_EDGES_C / CHUNK)

typedef unsigned short u16;

__device__ __forceinline__ float bf2f(u16 u) {
    unsigned int t = ((unsigned int)u) << 16;
    return __uint_as_float(t);
}
__device__ __forceinline__ u16 f2bf(float f) {  // round-to-nearest-even
    unsigned int x = __float_as_uint(f);
    x += 0x7fffu + ((x >> 16) & 1u);
    return (u16)(x >> 16);
}

// ============================ atomic-free bucketed partition ============================

__global__ __launch_bounds__(256) void passA_hist_kernel(const int* __restrict__ dst,
                                                         int* __restrict__ cnt, int n_edges) {
    __shared__ int h[NB];
    for (int i = threadIdx.x; i < NB; i += 256) h[i] = 0;
    __syncthreads();
    const int blk = blockIdx.x;
    const int end = min((blk + 1) * CHUNK, n_edges);
    for (int e = blk * CHUNK + threadIdx.x; e < end; e += 256)
        atomicAdd(&h[dst[e] >> 7], 1);
    __syncthreads();
    for (int i = threadIdx.x; i < NB; i += 256) cnt[i * NBLK + blk] = h[i];
}

__global__ __launch_bounds__(256) void scan_chunks_kernel(int* __restrict__ a, int n, int* __restrict__ bsums) {
    __shared__ int s[256];
    const int tid = threadIdx.x;
    int base = blockIdx.x * 1024 + tid * 4;
    int v[4];
#pragma unroll
    for (int i = 0; i < 4; ++i) v[i] = (base + i < n) ? a[base + i] : 0;
    int tsum = v[0] + v[1] + v[2] + v[3];
    s[tid] = tsum;
    __syncthreads();
    for (int off = 1; off < 256; off <<= 1) {
        int t = (tid >= off) ? s[tid - off] : 0;
        __syncthreads();
        s[tid] += t;
        __syncthreads();
    }
    int run = s[tid] - tsum;
#pragma unroll
    for (int i = 0; i < 4; ++i) {
        run += v[i];
        if (base + i < n) a[base + i] = run;
    }
    if (tid == 255) bsums[blockIdx.x] = s[255];
}

__global__ __launch_bounds__(256) void scan_sums_kernel(int* __restrict__ bsums, int nb) {
    __shared__ int s[256];
    const int tid = threadIdx.x;
    int v = (tid < nb) ? bsums[tid] : 0;
    s[tid] = v;
    __syncthreads();
    for (int off = 1; off < 256; off <<= 1) {
        int t = (tid >= off) ? s[tid - off] : 0;
        __syncthreads();
        s[tid] += t;
        __syncthreads();
    }
    if (tid < nb) bsums[tid] = s[tid] - v;
}

__global__ __launch_bounds__(256) void scan_add_kernel(int* __restrict__ a, int n, const int* __restrict__ bsums) {
    int base = blockIdx.x * 1024 + threadIdx.x * 4;
    int add = bsums[blockIdx.x];
#pragma unroll
    for (int i = 0; i < 4; ++i)
        if (base + i < n) a[base + i] += add;
}

__global__ __launch_bounds__(1024) void boffs_kernel(const int* __restrict__ incl,
                                                     int* __restrict__ boffs,
                                                     int* __restrict__ offs) {
    const int b = threadIdx.x;
    if (b < NB) boffs[b] = b ? incl[b * NBLK - 1] : 0;
    if (b == 0) {
        int total = incl[NB * NBLK - 1];
        boffs[NB] = total;
        offs[N_NODES_C] = total;
    }
}

__global__ __launch_bounds__(256) void passB_scatter_kernel(const int* __restrict__ src,
                                                            const int* __restrict__ dst,
                                                            const int* __restrict__ incl,
                                                            unsigned int* __restrict__ stage,
                                                            int n_edges) {
    __shared__ int cur[NB];
    const int blk = blockIdx.x;
    for (int i = threadIdx.x; i < NB; i += 256) {
        int idx = i * NBLK + blk;
        cur[i] = idx ? incl[idx - 1] : 0;
    }
    __syncthreads();
    const int end = min((blk + 1) * CHUNK, n_edges);
    for (int e = blk * CHUNK + threadIdx.x; e < end; e += 256) {
        int d = dst[e];
        int b = d >> 7;
        int pos = atomicAdd(&cur[b], 1);
        stage[pos] = (unsigned int)src[e] | ((unsigned int)(d & 127) << 17);
    }
}

__global__ __launch_bounds__(256) void bucket_finalize_kernel(const unsigned int* __restrict__ stage,
                                                              const int* __restrict__ boffs,
                                                              int* __restrict__ offs,
                                                              int* __restrict__ srcs) {
    __shared__ int hist[BNODES];
    __shared__ int excl[BNODES];
    __shared__ int curs[BNODES];
    __shared__ int sbuf[LDS_CAP];
    const int b = blockIdx.x, tid = threadIdx.x;
    const int base = boffs[b];
    const int count = boffs[b + 1] - base;
    const int n0 = b * BNODES;
    for (int i = tid; i < BNODES; i += 256) hist[i] = 0;
    __syncthreads();
    for (int i = tid; i < count; i += 256) {
        unsigned int w = stage[base + i];
        atomicAdd(&hist[w >> 17], 1);
    }
    __syncthreads();
    if (tid < BNODES) excl[tid] = hist[tid];
    __syncthreads();
    for (int off = 1; off < BNODES; off <<= 1) {
        int t = 0;
        if (tid < BNODES && tid >= off) t = excl[tid - off];
        __syncthreads();
        if (tid < BNODES) excl[tid] += t;
        __syncthreads();
    }
    if (tid < BNODES) {
        int ex = excl[tid] - hist[tid];
        int n = n0 + tid;
        if (n < N_NODES_C) offs[n] = base + ex;
        curs[tid] = ex;
    }
    __syncthreads();
    if (count <= LDS_CAP) {
        for (int i = tid; i < count; i += 256) {
            unsigned int w = stage[base + i];
            int p = atomicAdd(&curs[w >> 17], 1);
            sbuf[p] = (int)(w & 0x1FFFFu);
        }
        __syncthreads();
        for (int i = tid; i < count; i += 256) srcs[base + i] = sbuf[i];
    } else {
        for (int i = tid; i < count; i += 256) {
            unsigned int w = stage[base + i];
            int p = atomicAdd(&curs[w >> 17], 1);
            srcs[base + p] = (int)(w & 0x1FFFFu);
        }
    }
}

// ====== gather64 (bf16 feats): out[n] = relu(sum_{self+adj} feat[s] + bias), fp32 out ======

__global__ __launch_bounds__(256) void gather64_bf16_kernel(const u16* __restrict__ feat,
                                                            const int* __restrict__ offs,
                                                            const int* __restrict__ srcs,
                                                            const float* __restrict__ bias,
                                                            float* __restrict__ out, int n_nodes) {
    const int wave = threadIdx.x >> 6;
    const int lane = threadIdx.x & 63;
    const int n = blockIdx.x * 4 + wave;
    if (n >= n_nodes) return;
    float acc = bf2f(feat[(size_t)n * 64 + lane]);
    const int s0 = offs[n], s1 = offs[n + 1];
    int i = s0;
    for (; i + 8 <= s1; i += 8) {
        int sA[8];
#pragma unroll
        for (int u = 0; u < 8; ++u) sA[u] = srcs[i + u];
        u16 v[8];
#pragma unroll
        for (int u = 0; u < 8; ++u) v[u] = feat[(size_t)sA[u] * 64 + lane];
#pragma unroll
        for (int u = 0; u < 8; ++u) acc += bf2f(v[u]);
    }
    for (; i < s1; ++i) acc += bf2f(feat[(size_t)srcs[i] * 64 + lane]);
    acc = fmaxf(acc + bias[lane], 0.f);
    out[(size_t)n * 64 + lane] = acc;
}

// ============== dense: out = [relu](in @ W [+ b]), OUT=64; optional bf16 output ==============

template <int IN_DIM, bool RELU, bool HAS_BIAS, bool BF16_OUT>
__global__ __launch_bounds__(256) void mlp_layer_kernel(const float* __restrict__ in,
                                                        const float* __restrict__ W,
                                                        const float* __restrict__ bias,
                                                        void* __restrict__ out_v, int n_nodes) {
    __shared__ float sW[IN_DIM * 64];
    __shared__ float sB[64];
    __shared__ float sIn[64][IN_DIM + 4];
    const int tid = threadIdx.x;
    for (int i = tid; i < IN_DIM * 16; i += 256) ((float4*)sW)[i] = ((const float4*)W)[i];
    if (HAS_BIAS) {
        if (tid < 64) sB[tid] = bias[tid];
    }
    const int base = blockIdx.x * 64;
    for (int i = tid; i < 16 * IN_DIM; i += 256) {
        int nl = i / (IN_DIM / 4);
        int k4 = i % (IN_DIM / 4);
        int n = base + nl;
        float4 v = make_float4(0.f, 0.f, 0.f, 0.f);
        if (n < n_nodes) v = ((const float4*)in)[(size_t)n * (IN_DIM / 4) + k4];
        *(float4*)&sIn[nl][k4 * 4] = v;
    }
    __syncthreads();
    const int tj = tid & 15, tn = tid >> 4;
    const int j0 = tj * 4, n0 = tn * 4;
    float acc[4][4];
#pragma unroll
    for (int i = 0; i < 4; ++i)
#pragma unroll
        for (int j = 0; j < 4; ++j) acc[i][j] = HAS_BIAS ? sB[j0 + j] : 0.f;
    for (int k = 0; k < IN_DIM; k += 4) {
        float4 a0 = *(const float4*)&sIn[n0 + 0][k];
        float4 a1 = *(const float4*)&sIn[n0 + 1][k];
        float4 a2 = *(const float4*)&sIn[n0 + 2][k];
        float4 a3 = *(const float4*)&sIn[n0 + 3][k];
        float4 w0 = *(const float4*)&sW[(k + 0) * 64 + j0];
        float4 w1 = *(const float4*)&sW[(k + 1) * 64 + j0];
        float4 w2 = *(const float4*)&sW[(k + 2) * 64 + j0];
        float4 w3 = *(const float4*)&sW[(k + 3) * 64 + j0];
#define GIN_STEP(ai, i)                                                                               \
        acc[i][0] += ai.x * w0.x; acc[i][1] += ai.x * w0.y; acc[i][2] += ai.x * w0.z; acc[i][3] += ai.x * w0.w; \
        acc[i][0] += ai.y * w1.x; acc[i][1] += ai.y * w1.y; acc[i][2] += ai.y * w1.z; acc[i][3] += ai.y * w1.w; \
        acc[i][0] += ai.z * w2.x; acc[i][1] += ai.z * w2.y; acc[i][2] += ai.z * w2.z; acc[i][3] += ai.z * w2.w; \
        acc[i][0] += ai.w * w3.x; acc[i][1] += ai.w * w3.y; acc[i][2] += ai.w * w3.z; acc[i][3] += ai.w * w3.w;
        GIN_STEP(a0, 0) GIN_STEP(a1, 1) GIN_STEP(a2, 2) GIN_STEP(a3, 3)
#undef GIN_STEP
    }
#pragma unroll
    for (int i = 0; i < 4; ++i) {
        int n = base + n0 + i;
        if (n < n_nodes) {
            float r0 = RELU ? fmaxf(acc[i][0], 0.f) : acc[i][0];
            float r1 = RELU ? fmaxf(acc[i][1], 0.f) : acc[i][1];
            float r2 = RELU ? fmaxf(acc[i][2], 0.f) : acc[i][2];
            float r3 = RELU ? fmaxf(acc[i][3], 0.f) : acc[i][3];
            if (BF16_OUT) {
                ushort4 o;
                o.x = f2bf(r0); o.y = f2bf(r1); o.z = f2bf(r2); o.w = f2bf(r3);
                *(ushort4*)&((u16*)out_v)[(size_t)n * 64 + j0] = o;
            } else {
                float4 o = make_float4(r0, r1, r2, r3);
                *(float4*)&((float*)out_v)[(size_t)n * 64 + j0] = o;
            }
        }
    }
}

// ============================ final: log_softmax(in @ Wf + bf), IN=64, OUT=40 ============================

__global__ __launch_bounds__(256) void final_logsoftmax_kernel(const float* __restrict__ in,
                                                               const float* __restrict__ W,
                                                               const float* __restrict__ bias,
                                                               float* __restrict__ out, int n_nodes) {
    __shared__ float sW[64 * 40];
    __shared__ float sB[40];
    __shared__ float sIn[100][68];
    __shared__ float sLog[100][40];
    const int tid = threadIdx.x;
    for (int i = tid; i < 64 * 10; i += 256) ((float4*)sW)[i] = ((const float4*)W)[i];
    if (tid < 40) sB[tid] = bias[tid];
    const int base = blockIdx.x * 100;
    for (int i = tid; i < 100 * 16; i += 256) {
        int nl = i / 16, k4 = i % 16;
        int n = base + nl;
        float4 v = make_float4(0.f, 0.f, 0.f, 0.f);
        if (n < n_nodes) v = ((const float4*)in)[(size_t)n * 16 + k4];
        *(float4*)&sIn[nl][k4 * 4] = v;
    }
    __syncthreads();
    if (tid < 250) {
        const int tj = tid % 10, tn = tid / 10;
        const int j0 = tj * 4, n0 = tn * 4;
        float acc[4][4];
#pragma unroll
        for (int i = 0; i < 4; ++i)
#pragma unroll
            for (int j = 0; j < 4; ++j) acc[i][j] = sB[j0 + j];
        for (int k = 0; k < 64; k += 4) {
            float4 a0 = *(const float4*)&sIn[n0 + 0][k];
            float4 a1 = *(const float4*)&sIn[n0 + 1][k];
            float4 a2 = *(const float4*)&sIn[n0 + 2][k];
            float4 a3 = *(const float4*)&sIn[n0 + 3][k];
            float4 w0 = *(const float4*)&sW[(k + 0) * 40 + j0];
            float4 w1 = *(const float4*)&sW[(k + 1) * 40 + j0];
            float4 w2 = *(const float4*)&sW[(k + 2) * 40 + j0];
            float4 w3 = *(const float4*)&sW[(k + 3) * 40 + j0];
#define GIN_STEP(ai, i)                                                                               \
            acc[i][0] += ai.x * w0.x; acc[i][1] += ai.x * w0.y; acc[i][2] += ai.x * w0.z; acc[i][3] += ai.x * w0.w; \
            acc[i][0] += ai.y * w1.x; acc[i][1] += ai.y * w1.y; acc[i][2] += ai.y * w1.z; acc[i][3] += ai.y * w1.w; \
            acc[i][0] += ai.z * w2.x; acc[i][1] += ai.z * w2.y; acc[i][2] += ai.z * w2.z; acc[i][3] += ai.z * w2.w; \
            acc[i][0] += ai.w * w3.x; acc[i][1] += ai.w * w3.y; acc[i][2] += ai.w * w3.z; acc[i][3] += ai.w * w3.w;
            GIN_STEP(a0, 0) GIN_STEP(a1, 1) GIN_STEP(a2, 2) GIN_STEP(a3, 3)
#undef GIN_STEP
        }
#pragma unroll
        for (int i = 0; i < 4; ++i)
            *(float4*)&sLog[n0 + i][j0] = make_float4(acc[i][0], acc[i][1], acc[i][2], acc[i][3]);
    }
    __syncthreads();
    for (int nl = tid; nl < 100; nl += 256) {
        int n = base + nl;
        if (n >= n_nodes) continue;
        float m = -1e30f;
        for (int j = 0; j < 40; ++j) m = fmaxf(m, sLog[nl][j]);
        float s = 0.f;
        for (int j = 0; j < 40; ++j) s += expf(sLog[nl][j] - m);
        float lse = m + logf(s);
        for (int j = 0; j < 40; j += 4) {
            float4 o;
            o.x = sLog[nl][j + 0] - lse;
            o.y = sLog[nl][j + 1] - lse;
            o.z = sLog[nl][j + 2] - lse;
            o.w = sLog[nl][j + 3] - lse;
            *(float4*)&out[(size_t)n * 40 + j] = o;
        }
    }
}

// ============================ launch ============================

extern "C" void kernel_launch(void* const* d_in, const int* in_sizes, int n_in,
                              void* d_out, int out_size, void* d_ws, size_t ws_size,
                              hipStream_t stream) {
    const float* x  = (const float*)d_in[0];
    const int*   ei = (const int*)d_in[1];
    const float* W1 = (const float*)d_in[2];
    const float* b1 = (const float*)d_in[3];
    const float* W2 = (const float*)d_in[4];
    const float* b2 = (const float*)d_in[5];
    const float* W3 = (const float*)d_in[6];
    const float* b3 = (const float*)d_in[7];
    const float* W4 = (const float*)d_in[8];
    const float* b4 = (const float*)d_in[9];
    const float* Wf = (const float*)d_in[10];
    const float* bf = (const float*)d_in[11];
    float* outp = (float*)d_out;

    const int N = N_NODES_C, E = N_EDGES_C;
    const int* srcp = ei;
    const int* dstp = ei + E;

    // workspace layout (~90.6 MB)
    char* ws = (char*)d_ws;
    int*          offs  = (int*)(ws);                    // N+1 ints        -> 400128
    int*          boffs = (int*)(ws + 400128);           // NB+1 ints       -> 404352
    int*          bsums = (int*)(ws + 404352);           // 256 ints        -> 405376
    int*          cnt   = (int*)(ws + 405376);           // NB*NBLK ints    -> 1018624
    unsigned int* stage = (unsigned int*)(ws + 1018624); // E u32           -> 13818624
    int*          srcs  = (int*)(ws + 13818624);         // E ints          -> 26618624
    u16*          Ybf   = (u16*)(ws + 26618624);         // N*64 bf16       -> 39418624
    float*        F2    = (float*)(ws + 39418624);       // N*64 f32        -> 65018624
    float*        F3    = (float*)(ws + 65018624);       // N*64 f32        -> 90618624

    // ---- atomic-free bucketed CSR build ----
    passA_hist_kernel<<<NBLK, 256, 0, stream>>>(dstp, cnt, E);
    const int n_scan = NB * NBLK;
    const int nblk_scan = (n_scan + 1023) / 1024;
    scan_chunks_kernel<<<nblk_scan, 256, 0, stream>>>(cnt, n_scan, bsums);
    scan_sums_kernel<<<1, 256, 0, stream>>>(bsums, nblk_scan);
    scan_add_kernel<<<nblk_scan, 256, 0, stream>>>(cnt, n_scan, bsums);
    boffs_kernel<<<1, 1024, 0, stream>>>(cnt, boffs, offs);
    passB_scatter_kernel<<<NBLK, 256, 0, stream>>>(srcp, dstp, cnt, stage, E);
    bucket_finalize_kernel<<<NB, 256, 0, stream>>>(stage, boffs, offs, srcs);

    const int mlp_grid = (N + 63) / 64;
    const int gat_grid = (N + 3) / 4;

    // ---- conv1 via linearity: y = bf16(x@W1); h1 = relu(y_n + sum y_src + b1); c1r = relu(h1@W2+b2) ----
    mlp_layer_kernel<128, false, false, true><<<mlp_grid, 256, 0, stream>>>(x, W1, nullptr, Ybf, N);
    gather64_bf16_kernel<<<gat_grid, 256, 0, stream>>>(Ybf, offs, srcs, b1, F2, N);
    mlp_layer_kernel<64, true, true, false><<<mlp_grid, 256, 0, stream>>>(F2, W2, b2, F3, N);

    // ---- conv2 via linearity: u = bf16(c1r@W3); h3 = relu(u_n + sum u_src + b3); c2r = relu(h3@W4+b4) ----
    mlp_layer_kernel<64, false, false, true><<<mlp_grid, 256, 0, stream>>>(F3, W3, nullptr, Ybf, N);
    gather64_bf16_kernel<<<gat_grid, 256, 0, stream>>>(Ybf, offs, srcs, b3, F2, N);
    mlp_layer_kernel<64, true, true, false><<<mlp_grid, 256, 0, stream>>>(F2, W4, b4, F3, N);

    // ---- final fc + log_softmax ----
    final_logsoftmax_kernel<<<(N + 99) / 100, 256, 0, stream>>>(F3, Wf, bf, outp, N);
}

// Round 6
// 363.684 us; speedup vs baseline: 3.0921x; 1.0852x over previous
//
#include <hip/hip_runtime.h>
#include <math.h>

#define N_NODES_C 100000
#define N_EDGES_C 3200000
#define NB 782        // ceil(100000 / 128) buckets of 128 nodes
#define BNODES 128
#define LDS_CAP 6144  // per-bucket LDS staging capacity (mean ~4092, +32 sigma)
#define CHUNK 16384   // edges per partition block
#define NBLK 196      // ceil(N_EDGES_C / CHUNK)

typedef unsigned short u16;

__device__ __forceinline__ float bf2f(u16 u) {
    unsigned int t = ((unsigned int)u) << 16;
    return __uint_as_float(t);
}
__device__ __forceinline__ u16 f2bf(float f) {  // round-to-nearest-even
    unsigned int x = __float_as_uint(f);
    x += 0x7fffu + ((x >> 16) & 1u);
    return (u16)(x >> 16);
}

// ============================ atomic-free bucketed partition ============================

__global__ __launch_bounds__(256) void passA_hist_kernel(const int* __restrict__ dst,
                                                         int* __restrict__ cnt, int n_edges) {
    __shared__ int h[NB];
    for (int i = threadIdx.x; i < NB; i += 256) h[i] = 0;
    __syncthreads();
    const int blk = blockIdx.x;
    const int end = min((blk + 1) * CHUNK, n_edges);
    for (int e = blk * CHUNK + threadIdx.x; e < end; e += 256)
        atomicAdd(&h[dst[e] >> 7], 1);
    __syncthreads();
    for (int i = threadIdx.x; i < NB; i += 256) cnt[i * NBLK + blk] = h[i];
}

__global__ __launch_bounds__(256) void scan_chunks_kernel(int* __restrict__ a, int n, int* __restrict__ bsums) {
    __shared__ int s[256];
    const int tid = threadIdx.x;
    int base = blockIdx.x * 1024 + tid * 4;
    int v[4];
#pragma unroll
    for (int i = 0; i < 4; ++i) v[i] = (base + i < n) ? a[base + i] : 0;
    int tsum = v[0] + v[1] + v[2] + v[3];
    s[tid] = tsum;
    __syncthreads();
    for (int off = 1; off < 256; off <<= 1) {
        int t = (tid >= off) ? s[tid - off] : 0;
        __syncthreads();
        s[tid] += t;
        __syncthreads();
    }
    int run = s[tid] - tsum;
#pragma unroll
    for (int i = 0; i < 4; ++i) {
        run += v[i];
        if (base + i < n) a[base + i] = run;
    }
    if (tid == 255) bsums[blockIdx.x] = s[255];
}

__global__ __launch_bounds__(256) void scan_sums_kernel(int* __restrict__ bsums, int nb) {
    __shared__ int s[256];
    const int tid = threadIdx.x;
    int v = (tid < nb) ? bsums[tid] : 0;
    s[tid] = v;
    __syncthreads();
    for (int off = 1; off < 256; off <<= 1) {
        int t = (tid >= off) ? s[tid - off] : 0;
        __syncthreads();
        s[tid] += t;
        __syncthreads();
    }
    if (tid < nb) bsums[tid] = s[tid] - v;
}

__global__ __launch_bounds__(256) void scan_add_kernel(int* __restrict__ a, int n, const int* __restrict__ bsums) {
    int base = blockIdx.x * 1024 + threadIdx.x * 4;
    int add = bsums[blockIdx.x];
#pragma unroll
    for (int i = 0; i < 4; ++i)
        if (base + i < n) a[base + i] += add;
}

__global__ __launch_bounds__(1024) void boffs_kernel(const int* __restrict__ incl,
                                                     int* __restrict__ boffs,
                                                     int* __restrict__ offs) {
    const int b = threadIdx.x;
    if (b < NB) boffs[b] = b ? incl[b * NBLK - 1] : 0;
    if (b == 0) {
        int total = incl[NB * NBLK - 1];
        boffs[NB] = total;
        offs[N_NODES_C] = total;
    }
}

__global__ __launch_bounds__(256) void passB_scatter_kernel(const int* __restrict__ src,
                                                            const int* __restrict__ dst,
                                                            const int* __restrict__ incl,
                                                            unsigned int* __restrict__ stage,
                                                            int n_edges) {
    __shared__ int cur[NB];
    const int blk = blockIdx.x;
    for (int i = threadIdx.x; i < NB; i += 256) {
        int idx = i * NBLK + blk;
        cur[i] = idx ? incl[idx - 1] : 0;
    }
    __syncthreads();
    const int end = min((blk + 1) * CHUNK, n_edges);
    for (int e = blk * CHUNK + threadIdx.x; e < end; e += 256) {
        int d = dst[e];
        int b = d >> 7;
        int pos = atomicAdd(&cur[b], 1);
        stage[pos] = (unsigned int)src[e] | ((unsigned int)(d & 127) << 17);
    }
}

__global__ __launch_bounds__(256) void bucket_finalize_kernel(const unsigned int* __restrict__ stage,
                                                              const int* __restrict__ boffs,
                                                              int* __restrict__ offs,
                                                              int* __restrict__ srcs) {
    __shared__ int hist[BNODES];
    __shared__ int excl[BNODES];
    __shared__ int curs[BNODES];
    __shared__ int sbuf[LDS_CAP];
    const int b = blockIdx.x, tid = threadIdx.x;
    const int base = boffs[b];
    const int count = boffs[b + 1] - base;
    const int n0 = b * BNODES;
    for (int i = tid; i < BNODES; i += 256) hist[i] = 0;
    __syncthreads();
    for (int i = tid; i < count; i += 256) {
        unsigned int w = stage[base + i];
        atomicAdd(&hist[w >> 17], 1);
    }
    __syncthreads();
    if (tid < BNODES) excl[tid] = hist[tid];
    __syncthreads();
    for (int off = 1; off < BNODES; off <<= 1) {
        int t = 0;
        if (tid < BNODES && tid >= off) t = excl[tid - off];
        __syncthreads();
        if (tid < BNODES) excl[tid] += t;
        __syncthreads();
    }
    if (tid < BNODES) {
        int ex = excl[tid] - hist[tid];
        int n = n0 + tid;
        if (n < N_NODES_C) offs[n] = base + ex;
        curs[tid] = ex;
    }
    __syncthreads();
    if (count <= LDS_CAP) {
        for (int i = tid; i < count; i += 256) {
            unsigned int w = stage[base + i];
            int p = atomicAdd(&curs[w >> 17], 1);
            sbuf[p] = (int)(w & 0x1FFFFu);
        }
        __syncthreads();
        for (int i = tid; i < count; i += 256) srcs[base + i] = sbuf[i];
    } else {
        for (int i = tid; i < count; i += 256) {
            unsigned int w = stage[base + i];
            int p = atomicAdd(&curs[w >> 17], 1);
            srcs[base + p] = (int)(w & 0x1FFFFu);
        }
    }
}

// ====== gather64v (bf16 feats, vectorized): 16 lanes/row, 4 row-slots/wave, 2-deep unroll ======
// out[n] = relu(sum_{self+adj(n)} feat[s] + bias), fp32 out

__global__ __launch_bounds__(256) void gather64v_kernel(const u16* __restrict__ feat,
                                                        const int* __restrict__ offs,
                                                        const int* __restrict__ srcs,
                                                        const float* __restrict__ bias,
                                                        float* __restrict__ out, int n_nodes) {
    const int wave = threadIdx.x >> 6;
    const int lane = threadIdx.x & 63;
    const int grp  = lane >> 4;   // row slot 0..3
    const int cl   = lane & 15;   // channel quad: channels cl*4 .. cl*4+3
    const int n = blockIdx.x * 4 + wave;
    if (n >= n_nodes) return;

    float a0 = 0.f, a1 = 0.f, a2 = 0.f, a3 = 0.f;
    if (grp == 0) {  // self feature counted once
        ushort4 v = *(const ushort4*)&feat[(size_t)n * 64 + cl * 4];
        a0 = bf2f(v.x); a1 = bf2f(v.y); a2 = bf2f(v.z); a3 = bf2f(v.w);
    }
    const int s0 = offs[n], s1 = offs[n + 1];
    int i = s0;
    for (; i + 8 <= s1; i += 8) {  // 8 rows per iter: group g takes rows i+g, i+4+g
        int r0 = srcs[i + grp];
        int r1 = srcs[i + 4 + grp];
        ushort4 v0 = *(const ushort4*)&feat[(size_t)r0 * 64 + cl * 4];
        ushort4 v1 = *(const ushort4*)&feat[(size_t)r1 * 64 + cl * 4];
        a0 += bf2f(v0.x); a1 += bf2f(v0.y); a2 += bf2f(v0.z); a3 += bf2f(v0.w);
        a0 += bf2f(v1.x); a1 += bf2f(v1.y); a2 += bf2f(v1.z); a3 += bf2f(v1.w);
    }
    for (; i + 4 <= s1; i += 4) {  // 4-row step
        int r = srcs[i + grp];
        ushort4 v = *(const ushort4*)&feat[(size_t)r * 64 + cl * 4];
        a0 += bf2f(v.x); a1 += bf2f(v.y); a2 += bf2f(v.z); a3 += bf2f(v.w);
    }
    if (i + grp < s1) {            // tail 0..3 rows
        int r = srcs[i + grp];
        ushort4 v = *(const ushort4*)&feat[(size_t)r * 64 + cl * 4];
        a0 += bf2f(v.x); a1 += bf2f(v.y); a2 += bf2f(v.z); a3 += bf2f(v.w);
    }
    // reduce the 4 row-slot groups (lanes differ only in bits 4-5)
    a0 += __shfl_xor(a0, 16); a1 += __shfl_xor(a1, 16);
    a2 += __shfl_xor(a2, 16); a3 += __shfl_xor(a3, 16);
    a0 += __shfl_xor(a0, 32); a1 += __shfl_xor(a1, 32);
    a2 += __shfl_xor(a2, 32); a3 += __shfl_xor(a3, 32);
    if (lane < 16) {
        float4 b = *(const float4*)&bias[cl * 4];
        float4 o;
        o.x = fmaxf(a0 + b.x, 0.f);
        o.y = fmaxf(a1 + b.y, 0.f);
        o.z = fmaxf(a2 + b.z, 0.f);
        o.w = fmaxf(a3 + b.w, 0.f);
        *(float4*)&out[(size_t)n * 64 + cl * 4] = o;
    }
}

// ============== dense: out = [relu](in @ W [+ b]), OUT=64; optional bf16 output ==============

template <int IN_DIM, bool RELU, bool HAS_BIAS, bool BF16_OUT>
__global__ __launch_bounds__(256) void mlp_layer_kernel(const float* __restrict__ in,
                                                        const float* __restrict__ W,
                                                        const float* __restrict__ bias,
                                                        void* __restrict__ out_v, int n_nodes) {
    __shared__ float sW[IN_DIM * 64];
    __shared__ float sB[64];
    __shared__ float sIn[64][IN_DIM + 4];
    const int tid = threadIdx.x;
    for (int i = tid; i < IN_DIM * 16; i += 256) ((float4*)sW)[i] = ((const float4*)W)[i];
    if (HAS_BIAS) {
        if (tid < 64) sB[tid] = bias[tid];
    }
    const int base = blockIdx.x * 64;
    for (int i = tid; i < 16 * IN_DIM; i += 256) {
        int nl = i / (IN_DIM / 4);
        int k4 = i % (IN_DIM / 4);
        int n = base + nl;
        float4 v = make_float4(0.f, 0.f, 0.f, 0.f);
        if (n < n_nodes) v = ((const float4*)in)[(size_t)n * (IN_DIM / 4) + k4];
        *(float4*)&sIn[nl][k4 * 4] = v;
    }
    __syncthreads();
    const int tj = tid & 15, tn = tid >> 4;
    const int j0 = tj * 4, n0 = tn * 4;
    float acc[4][4];
#pragma unroll
    for (int i = 0; i < 4; ++i)
#pragma unroll
        for (int j = 0; j < 4; ++j) acc[i][j] = HAS_BIAS ? sB[j0 + j] : 0.f;
    for (int k = 0; k < IN_DIM; k += 4) {
        float4 a0 = *(const float4*)&sIn[n0 + 0][k];
        float4 a1 = *(const float4*)&sIn[n0 + 1][k];
        float4 a2 = *(const float4*)&sIn[n0 + 2][k];
        float4 a3 = *(const float4*)&sIn[n0 + 3][k];
        float4 w0 = *(const float4*)&sW[(k + 0) * 64 + j0];
        float4 w1 = *(const float4*)&sW[(k + 1) * 64 + j0];
        float4 w2 = *(const float4*)&sW[(k + 2) * 64 + j0];
        float4 w3 = *(const float4*)&sW[(k + 3) * 64 + j0];
#define GIN_STEP(ai, i)                                                                               \
        acc[i][0] += ai.x * w0.x; acc[i][1] += ai.x * w0.y; acc[i][2] += ai.x * w0.z; acc[i][3] += ai.x * w0.w; \
        acc[i][0] += ai.y * w1.x; acc[i][1] += ai.y * w1.y; acc[i][2] += ai.y * w1.z; acc[i][3] += ai.y * w1.w; \
        acc[i][0] += ai.z * w2.x; acc[i][1] += ai.z * w2.y; acc[i][2] += ai.z * w2.z; acc[i][3] += ai.z * w2.w; \
        acc[i][0] += ai.w * w3.x; acc[i][1] += ai.w * w3.y; acc[i][2] += ai.w * w3.z; acc[i][3] += ai.w * w3.w;
        GIN_STEP(a0, 0) GIN_STEP(a1, 1) GIN_STEP(a2, 2) GIN_STEP(a3, 3)
#undef GIN_STEP
    }
#pragma unroll
    for (int i = 0; i < 4; ++i) {
        int n = base + n0 + i;
        if (n < n_nodes) {
            float r0 = RELU ? fmaxf(acc[i][0], 0.f) : acc[i][0];
            float r1 = RELU ? fmaxf(acc[i][1], 0.f) : acc[i][1];
            float r2 = RELU ? fmaxf(acc[i][2], 0.f) : acc[i][2];
            float r3 = RELU ? fmaxf(acc[i][3], 0.f) : acc[i][3];
            if (BF16_OUT) {
                ushort4 o;
                o.x = f2bf(r0); o.y = f2bf(r1); o.z = f2bf(r2); o.w = f2bf(r3);
                *(ushort4*)&((u16*)out_v)[(size_t)n * 64 + j0] = o;
            } else {
                float4 o = make_float4(r0, r1, r2, r3);
                *(float4*)&((float*)out_v)[(size_t)n * 64 + j0] = o;
            }
        }
    }
}

// ============================ final: log_softmax(in @ Wf + bf), IN=64, OUT=40 ============================

__global__ __launch_bounds__(256) void final_logsoftmax_kernel(const float* __restrict__ in,
                                                               const float* __restrict__ W,
                                                               const float* __restrict__ bias,
                                                               float* __restrict__ out, int n_nodes) {
    __shared__ float sW[64 * 40];
    __shared__ float sB[40];
    __shared__ float sIn[100][68];
    __shared__ float sLog[100][40];
    const int tid = threadIdx.x;
    for (int i = tid; i < 64 * 10; i += 256) ((float4*)sW)[i] = ((const float4*)W)[i];
    if (tid < 40) sB[tid] = bias[tid];
    const int base = blockIdx.x * 100;
    for (int i = tid; i < 100 * 16; i += 256) {
        int nl = i / 16, k4 = i % 16;
        int n = base + nl;
        float4 v = make_float4(0.f, 0.f, 0.f, 0.f);
        if (n < n_nodes) v = ((const float4*)in)[(size_t)n * 16 + k4];
        *(float4*)&sIn[nl][k4 * 4] = v;
    }
    __syncthreads();
    if (tid < 250) {
        const int tj = tid % 10, tn = tid / 10;
        const int j0 = tj * 4, n0 = tn * 4;
        float acc[4][4];
#pragma unroll
        for (int i = 0; i < 4; ++i)
#pragma unroll
            for (int j = 0; j < 4; ++j) acc[i][j] = sB[j0 + j];
        for (int k = 0; k < 64; k += 4) {
            float4 a0 = *(const float4*)&sIn[n0 + 0][k];
            float4 a1 = *(const float4*)&sIn[n0 + 1][k];
            float4 a2 = *(const float4*)&sIn[n0 + 2][k];
            float4 a3 = *(const float4*)&sIn[n0 + 3][k];
            float4 w0 = *(const float4*)&sW[(k + 0) * 40 + j0];
            float4 w1 = *(const float4*)&sW[(k + 1) * 40 + j0];
            float4 w2 = *(const float4*)&sW[(k + 2) * 40 + j0];
            float4 w3 = *(const float4*)&sW[(k + 3) * 40 + j0];
#define GIN_STEP(ai, i)                                                                               \
            acc[i][0] += ai.x * w0.x; acc[i][1] += ai.x * w0.y; acc[i][2] += ai.x * w0.z; acc[i][3] += ai.x * w0.w; \
            acc[i][0] += ai.y * w1.x; acc[i][1] += ai.y * w1.y; acc[i][2] += ai.y * w1.z; acc[i][3] += ai.y * w1.w; \
            acc[i][0] += ai.z * w2.x; acc[i][1] += ai.z * w2.y; acc[i][2] += ai.z * w2.z; acc[i][3] += ai.z * w2.w; \
            acc[i][0] += ai.w * w3.x; acc[i][1] += ai.w * w3.y; acc[i][2] += ai.w * w3.z; acc[i][3] += ai.w * w3.w;
            GIN_STEP(a0, 0) GIN_STEP(a1, 1) GIN_STEP(a2, 2) GIN_STEP(a3, 3)
#undef GIN_STEP
        }
#pragma unroll
        for (int i = 0; i < 4; ++i)
            *(float4*)&sLog[n0 + i][j0] = make_float4(acc[i][0], acc[i][1], acc[i][2], acc[i][3]);
    }
    __syncthreads();
    for (int nl = tid; nl < 100; nl += 256) {
        int n = base + nl;
        if (n >= n_nodes) continue;
        float m = -1e30f;
        for (int j = 0; j < 40; ++j) m = fmaxf(m, sLog[nl][j]);
        float s = 0.f;
        for (int j = 0; j < 40; ++j) s += expf(sLog[nl][j] - m);
        float lse = m + logf(s);
        for (int j = 0; j < 40; j += 4) {
            float4 o;
            o.x = sLog[nl][j + 0] - lse;
            o.y = sLog[nl][j + 1] - lse;
            o.z = sLog[nl][j + 2] - lse;
            o.w = sLog[nl][j + 3] - lse;
            *(float4*)&out[(size_t)n * 40 + j] = o;
        }
    }
}

// ============================ launch ============================

extern "C" void kernel_launch(void* const* d_in, const int* in_sizes, int n_in,
                              void* d_out, int out_size, void* d_ws, size_t ws_size,
                              hipStream_t stream) {
    const float* x  = (const float*)d_in[0];
    const int*   ei = (const int*)d_in[1];
    const float* W1 = (const float*)d_in[2];
    const float* b1 = (const float*)d_in[3];
    const float* W2 = (const float*)d_in[4];
    const float* b2 = (const float*)d_in[5];
    const float* W3 = (const float*)d_in[6];
    const float* b3 = (const float*)d_in[7];
    const float* W4 = (const float*)d_in[8];
    const float* b4 = (const float*)d_in[9];
    const float* Wf = (const float*)d_in[10];
    const float* bf = (const float*)d_in[11];
    float* outp = (float*)d_out;

    const int N = N_NODES_C, E = N_EDGES_C;
    const int* srcp = ei;
    const int* dstp = ei + E;

    // workspace layout (~90.6 MB)
    char* ws = (char*)d_ws;
    int*          offs  = (int*)(ws);                    // N+1 ints        -> 400128
    int*          boffs = (int*)(ws + 400128);           // NB+1 ints       -> 404352
    int*          bsums = (int*)(ws + 404352);           // 256 ints        -> 405376
    int*          cnt   = (int*)(ws + 405376);           // NB*NBLK ints    -> 1018624
    unsigned int* stage = (unsigned int*)(ws + 1018624); // E u32           -> 13818624
    int*          srcs  = (int*)(ws + 13818624);         // E ints          -> 26618624
    u16*          Ybf   = (u16*)(ws + 26618624);         // N*64 bf16       -> 39418624
    float*        F2    = (float*)(ws + 39418624);       // N*64 f32        -> 65018624
    float*        F3    = (float*)(ws + 65018624);       // N*64 f32        -> 90618624

    // ---- atomic-free bucketed CSR build ----
    passA_hist_kernel<<<NBLK, 256, 0, stream>>>(dstp, cnt, E);
    const int n_scan = NB * NBLK;
    const int nblk_scan = (n_scan + 1023) / 1024;
    scan_chunks_kernel<<<nblk_scan, 256, 0, stream>>>(cnt, n_scan, bsums);
    scan_sums_kernel<<<1, 256, 0, stream>>>(bsums, nblk_scan);
    scan_add_kernel<<<nblk_scan, 256, 0, stream>>>(cnt, n_scan, bsums);
    boffs_kernel<<<1, 1024, 0, stream>>>(cnt, boffs, offs);
    passB_scatter_kernel<<<NBLK, 256, 0, stream>>>(srcp, dstp, cnt, stage, E);
    bucket_finalize_kernel<<<NB, 256, 0, stream>>>(stage, boffs, offs, srcs);

    const int mlp_grid = (N + 63) / 64;
    const int gat_grid = (N + 3) / 4;

    // ---- conv1 via linearity: y = bf16(x@W1); h1 = relu(y_n + sum y_src + b1); c1r = relu(h1@W2+b2) ----
    mlp_layer_kernel<128, false, false, true><<<mlp_grid, 256, 0, stream>>>(x, W1, nullptr, Ybf, N);
    gather64v_kernel<<<gat_grid, 256, 0, stream>>>(Ybf, offs, srcs, b1, F2, N);
    mlp_layer_kernel<64, true, true, false><<<mlp_grid, 256, 0, stream>>>(F2, W2, b2, F3, N);

    // ---- conv2 via linearity: u = bf16(c1r@W3); h3 = relu(u_n + sum u_src + b3); c2r = relu(h3@W4+b4) ----
    mlp_layer_kernel<64, false, false, true><<<mlp_grid, 256, 0, stream>>>(F3, W3, nullptr, Ybf, N);
    gather64v_kernel<<<gat_grid, 256, 0, stream>>>(Ybf, offs, srcs, b3, F2, N);
    mlp_layer_kernel<64, true, true, false><<<mlp_grid, 256, 0, stream>>>(F2, W4, b4, F3, N);

    // ---- final fc + log_softmax ----
    final_logsoftmax_kernel<<<(N + 99) / 100, 256, 0, stream>>>(F3, Wf, bf, outp, N);
}

// Round 7
// 344.003 us; speedup vs baseline: 3.2690x; 1.0572x over previous
//
#include <hip/hip_runtime.h>
#include <math.h>

#define N_NODES_C 100000
#define N_EDGES_C 3200000
#define NB 782        // ceil(100000 / 128) buckets of 128 nodes
#define BNODES 128
#define LDS_CAP 6144  // per-bucket LDS staging capacity (mean ~4092, +32 sigma)
#define CHUNK 16384   // edges per partition block
#define NBLK 196      // ceil(N_EDGES_C / CHUNK)

typedef unsigned short u16;

__device__ __forceinline__ float bf2f(u16 u) {
    unsigned int t = ((unsigned int)u) << 16;
    return __uint_as_float(t);
}
__device__ __forceinline__ u16 f2bf(float f) {  // round-to-nearest-even
    unsigned int x = __float_as_uint(f);
    x += 0x7fffu + ((x >> 16) & 1u);
    return (u16)(x >> 16);
}

// ============================ atomic-free bucketed partition ============================

__global__ __launch_bounds__(256) void passA_hist_kernel(const int* __restrict__ dst,
                                                         int* __restrict__ cnt, int n_edges) {
    __shared__ int h[NB];
    for (int i = threadIdx.x; i < NB; i += 256) h[i] = 0;
    __syncthreads();
    const int blk = blockIdx.x;
    const int end = min((blk + 1) * CHUNK, n_edges);
    for (int e = blk * CHUNK + threadIdx.x; e < end; e += 256)
        atomicAdd(&h[dst[e] >> 7], 1);
    __syncthreads();
    for (int i = threadIdx.x; i < NB; i += 256) cnt[i * NBLK + blk] = h[i];
}

__global__ __launch_bounds__(256) void scan_chunks_kernel(int* __restrict__ a, int n, int* __restrict__ bsums) {
    __shared__ int s[256];
    const int tid = threadIdx.x;
    int base = blockIdx.x * 1024 + tid * 4;
    int v[4];
#pragma unroll
    for (int i = 0; i < 4; ++i) v[i] = (base + i < n) ? a[base + i] : 0;
    int tsum = v[0] + v[1] + v[2] + v[3];
    s[tid] = tsum;
    __syncthreads();
    for (int off = 1; off < 256; off <<= 1) {
        int t = (tid >= off) ? s[tid - off] : 0;
        __syncthreads();
        s[tid] += t;
        __syncthreads();
    }
    int run = s[tid] - tsum;
#pragma unroll
    for (int i = 0; i < 4; ++i) {
        run += v[i];
        if (base + i < n) a[base + i] = run;
    }
    if (tid == 255) bsums[blockIdx.x] = s[255];
}

__global__ __launch_bounds__(256) void scan_sums_kernel(int* __restrict__ bsums, int nb) {
    __shared__ int s[256];
    const int tid = threadIdx.x;
    int v = (tid < nb) ? bsums[tid] : 0;
    s[tid] = v;
    __syncthreads();
    for (int off = 1; off < 256; off <<= 1) {
        int t = (tid >= off) ? s[tid - off] : 0;
        __syncthreads();
        s[tid] += t;
        __syncthreads();
    }
    if (tid < nb) bsums[tid] = s[tid] - v;
}

__global__ __launch_bounds__(256) void scan_add_kernel(int* __restrict__ a, int n, const int* __restrict__ bsums) {
    int base = blockIdx.x * 1024 + threadIdx.x * 4;
    int add = bsums[blockIdx.x];
#pragma unroll
    for (int i = 0; i < 4; ++i)
        if (base + i < n) a[base + i] += add;
}

__global__ __launch_bounds__(1024) void boffs_kernel(const int* __restrict__ incl,
                                                     int* __restrict__ boffs,
                                                     int* __restrict__ offs) {
    const int b = threadIdx.x;
    if (b < NB) boffs[b] = b ? incl[b * NBLK - 1] : 0;
    if (b == 0) {
        int total = incl[NB * NBLK - 1];
        boffs[NB] = total;
        offs[N_NODES_C] = total;
    }
}

// pass B (LDS sort): block-local counting sort by bucket, then burst-write each run
__global__ __launch_bounds__(256) void passB_sort_kernel(const int* __restrict__ src,
                                                         const int* __restrict__ dst,
                                                         const int* __restrict__ incl,
                                                         unsigned int* __restrict__ stage,
                                                         int n_edges) {
    __shared__ unsigned int sdst[CHUNK];    // 64 KB
    __shared__ unsigned int spack[CHUNK];   // 64 KB
    __shared__ int hist[NB];                // -> lbase after scan
    __shared__ int lcur[NB];
    __shared__ int tsum[256];
    const int blk = blockIdx.x, tid = threadIdx.x;
    const int e0 = blk * CHUNK;
    const int cntE = min(CHUNK, n_edges - e0);

    for (int b = tid; b < NB; b += 256) hist[b] = 0;
    __syncthreads();

    // P1: load dst -> LDS, histogram buckets
    if (cntE == CHUNK) {
        for (int i = tid * 4; i < CHUNK; i += 1024) {
            int4 d4 = *(const int4*)&dst[e0 + i];
            sdst[i + 0] = (unsigned)d4.x; sdst[i + 1] = (unsigned)d4.y;
            sdst[i + 2] = (unsigned)d4.z; sdst[i + 3] = (unsigned)d4.w;
            atomicAdd(&hist[d4.x >> 7], 1); atomicAdd(&hist[d4.y >> 7], 1);
            atomicAdd(&hist[d4.z >> 7], 1); atomicAdd(&hist[d4.w >> 7], 1);
        }
    } else {
        for (int i = tid; i < cntE; i += 256) {
            int d = dst[e0 + i];
            sdst[i] = (unsigned)d;
            atomicAdd(&hist[d >> 7], 1);
        }
    }
    __syncthreads();

    // P2: block-exclusive scan of hist[0..NB) -> hist=lbase, lcur=lbase
    {
        int loc[4];
        const int bi = tid * 4;
        int s = 0;
#pragma unroll
        for (int k = 0; k < 4; ++k) {
            int idx = bi + k;
            loc[k] = (idx < NB) ? hist[idx] : 0;
            s += loc[k];
        }
        tsum[tid] = s;
        __syncthreads();
        for (int off = 1; off < 256; off <<= 1) {
            int t = (tid >= off) ? tsum[tid - off] : 0;
            __syncthreads();
            tsum[tid] += t;
            __syncthreads();
        }
        int run = tsum[tid] - s;
#pragma unroll
        for (int k = 0; k < 4; ++k) {
            int idx = bi + k;
            if (idx < NB) {
                int h = loc[k];
                hist[idx] = run;
                lcur[idx] = run;
                run += h;
            }
        }
    }
    __syncthreads();

    // P3: scatter into spack, sorted by bucket (LDS atomics only)
    if (cntE == CHUNK) {
        for (int i = tid * 4; i < CHUNK; i += 1024) {
            int4 s4 = *(const int4*)&src[e0 + i];
            unsigned int d; int p;
            d = sdst[i + 0]; p = atomicAdd(&lcur[d >> 7], 1); spack[p] = (unsigned)s4.x | ((d & 127u) << 17);
            d = sdst[i + 1]; p = atomicAdd(&lcur[d >> 7], 1); spack[p] = (unsigned)s4.y | ((d & 127u) << 17);
            d = sdst[i + 2]; p = atomicAdd(&lcur[d >> 7], 1); spack[p] = (unsigned)s4.z | ((d & 127u) << 17);
            d = sdst[i + 3]; p = atomicAdd(&lcur[d >> 7], 1); spack[p] = (unsigned)s4.w | ((d & 127u) << 17);
        }
    } else {
        for (int i = tid; i < cntE; i += 256) {
            unsigned int d = sdst[i];
            int p = atomicAdd(&lcur[d >> 7], 1);
            spack[p] = (unsigned)src[e0 + i] | ((d & 127u) << 17);
        }
    }
    __syncthreads();

    // P4: burst-write each bucket run to its reserved global range
    for (int b = tid; b < NB; b += 256) {
        int l0 = hist[b];
        int l1 = (b + 1 < NB) ? hist[b + 1] : cntE;
        int idx = b * NBLK + blk;
        int g0 = idx ? incl[idx - 1] : 0;
        for (int j = l0; j < l1; ++j) stage[g0 + (j - l0)] = spack[j];
    }
}

__global__ __launch_bounds__(256) void bucket_finalize_kernel(const unsigned int* __restrict__ stage,
                                                              const int* __restrict__ boffs,
                                                              int* __restrict__ offs,
                                                              int* __restrict__ srcs) {
    __shared__ int hist[BNODES];
    __shared__ int excl[BNODES];
    __shared__ int curs[BNODES];
    __shared__ int sbuf[LDS_CAP];
    const int b = blockIdx.x, tid = threadIdx.x;
    const int base = boffs[b];
    const int count = boffs[b + 1] - base;
    const int n0 = b * BNODES;
    for (int i = tid; i < BNODES; i += 256) hist[i] = 0;
    __syncthreads();
    for (int i = tid; i < count; i += 256) {
        unsigned int w = stage[base + i];
        atomicAdd(&hist[w >> 17], 1);
    }
    __syncthreads();
    if (tid < BNODES) excl[tid] = hist[tid];
    __syncthreads();
    for (int off = 1; off < BNODES; off <<= 1) {
        int t = 0;
        if (tid < BNODES && tid >= off) t = excl[tid - off];
        __syncthreads();
        if (tid < BNODES) excl[tid] += t;
        __syncthreads();
    }
    if (tid < BNODES) {
        int ex = excl[tid] - hist[tid];
        int n = n0 + tid;
        if (n < N_NODES_C) offs[n] = base + ex;
        curs[tid] = ex;
    }
    __syncthreads();
    if (count <= LDS_CAP) {
        for (int i = tid; i < count; i += 256) {
            unsigned int w = stage[base + i];
            int p = atomicAdd(&curs[w >> 17], 1);
            sbuf[p] = (int)(w & 0x1FFFFu);
        }
        __syncthreads();
        for (int i = tid; i < count; i += 256) srcs[base + i] = sbuf[i];
    } else {
        for (int i = tid; i < count; i += 256) {
            unsigned int w = stage[base + i];
            int p = atomicAdd(&curs[w >> 17], 1);
            srcs[base + p] = (int)(w & 0x1FFFFu);
        }
    }
}

// ====== gather64v (bf16 feats, vectorized): 16 lanes/row, 4 row-slots/wave, 2-deep unroll ======

__global__ __launch_bounds__(256) void gather64v_kernel(const u16* __restrict__ feat,
                                                        const int* __restrict__ offs,
                                                        const int* __restrict__ srcs,
                                                        const float* __restrict__ bias,
                                                        float* __restrict__ out, int n_nodes) {
    const int wave = threadIdx.x >> 6;
    const int lane = threadIdx.x & 63;
    const int grp  = lane >> 4;
    const int cl   = lane & 15;
    const int n = blockIdx.x * 4 + wave;
    if (n >= n_nodes) return;

    float a0 = 0.f, a1 = 0.f, a2 = 0.f, a3 = 0.f;
    if (grp == 0) {
        ushort4 v = *(const ushort4*)&feat[(size_t)n * 64 + cl * 4];
        a0 = bf2f(v.x); a1 = bf2f(v.y); a2 = bf2f(v.z); a3 = bf2f(v.w);
    }
    const int s0 = offs[n], s1 = offs[n + 1];
    int i = s0;
    for (; i + 8 <= s1; i += 8) {
        int r0 = srcs[i + grp];
        int r1 = srcs[i + 4 + grp];
        ushort4 v0 = *(const ushort4*)&feat[(size_t)r0 * 64 + cl * 4];
        ushort4 v1 = *(const ushort4*)&feat[(size_t)r1 * 64 + cl * 4];
        a0 += bf2f(v0.x); a1 += bf2f(v0.y); a2 += bf2f(v0.z); a3 += bf2f(v0.w);
        a0 += bf2f(v1.x); a1 += bf2f(v1.y); a2 += bf2f(v1.z); a3 += bf2f(v1.w);
    }
    for (; i + 4 <= s1; i += 4) {
        int r = srcs[i + grp];
        ushort4 v = *(const ushort4*)&feat[(size_t)r * 64 + cl * 4];
        a0 += bf2f(v.x); a1 += bf2f(v.y); a2 += bf2f(v.z); a3 += bf2f(v.w);
    }
    if (i + grp < s1) {
        int r = srcs[i + grp];
        ushort4 v = *(const ushort4*)&feat[(size_t)r * 64 + cl * 4];
        a0 += bf2f(v.x); a1 += bf2f(v.y); a2 += bf2f(v.z); a3 += bf2f(v.w);
    }
    a0 += __shfl_xor(a0, 16); a1 += __shfl_xor(a1, 16);
    a2 += __shfl_xor(a2, 16); a3 += __shfl_xor(a3, 16);
    a0 += __shfl_xor(a0, 32); a1 += __shfl_xor(a1, 32);
    a2 += __shfl_xor(a2, 32); a3 += __shfl_xor(a3, 32);
    if (lane < 16) {
        float4 b = *(const float4*)&bias[cl * 4];
        float4 o;
        o.x = fmaxf(a0 + b.x, 0.f);
        o.y = fmaxf(a1 + b.y, 0.f);
        o.z = fmaxf(a2 + b.z, 0.f);
        o.w = fmaxf(a3 + b.w, 0.f);
        *(float4*)&out[(size_t)n * 64 + cl * 4] = o;
    }
}

// ============== dense: out = [relu](in @ W [+ b]), OUT=64; optional bf16 output ==============

template <int IN_DIM, bool RELU, bool HAS_BIAS, bool BF16_OUT>
__global__ __launch_bounds__(256) void mlp_layer_kernel(const float* __restrict__ in,
                                                        const float* __restrict__ W,
                                                        const float* __restrict__ bias,
                                                        void* __restrict__ out_v, int n_nodes) {
    __shared__ float sW[IN_DIM * 64];
    __shared__ float sB[64];
    __shared__ float sIn[64][IN_DIM + 4];
    const int tid = threadIdx.x;
    for (int i = tid; i < IN_DIM * 16; i += 256) ((float4*)sW)[i] = ((const float4*)W)[i];
    if (HAS_BIAS) {
        if (tid < 64) sB[tid] = bias[tid];
    }
    const int base = blockIdx.x * 64;
    for (int i = tid; i < 16 * IN_DIM; i += 256) {
        int nl = i / (IN_DIM / 4);
        int k4 = i % (IN_DIM / 4);
        int n = base + nl;
        float4 v = make_float4(0.f, 0.f, 0.f, 0.f);
        if (n < n_nodes) v = ((const float4*)in)[(size_t)n * (IN_DIM / 4) + k4];
        *(float4*)&sIn[nl][k4 * 4] = v;
    }
    __syncthreads();
    const int tj = tid & 15, tn = tid >> 4;
    const int j0 = tj * 4, n0 = tn * 4;
    float acc[4][4];
#pragma unroll
    for (int i = 0; i < 4; ++i)
#pragma unroll
        for (int j = 0; j < 4; ++j) acc[i][j] = HAS_BIAS ? sB[j0 + j] : 0.f;
    for (int k = 0; k < IN_DIM; k += 4) {
        float4 a0 = *(const float4*)&sIn[n0 + 0][k];
        float4 a1 = *(const float4*)&sIn[n0 + 1][k];
        float4 a2 = *(const float4*)&sIn[n0 + 2][k];
        float4 a3 = *(const float4*)&sIn[n0 + 3][k];
        float4 w0 = *(const float4*)&sW[(k + 0) * 64 + j0];
        float4 w1 = *(const float4*)&sW[(k + 1) * 64 + j0];
        float4 w2 = *(const float4*)&sW[(k + 2) * 64 + j0];
        float4 w3 = *(const float4*)&sW[(k + 3) * 64 + j0];
#define GIN_STEP(ai, i)                                                                               \
        acc[i][0] += ai.x * w0.x; acc[i][1] += ai.x * w0.y; acc[i][2] += ai.x * w0.z; acc[i][3] += ai.x * w0.w; \
        acc[i][0] += ai.y * w1.x; acc[i][1] += ai.y * w1.y; acc[i][2] += ai.y * w1.z; acc[i][3] += ai.y * w1.w; \
        acc[i][0] += ai.z * w2.x; acc[i][1] += ai.z * w2.y; acc[i][2] += ai.z * w2.z; acc[i][3] += ai.z * w2.w; \
        acc[i][0] += ai.w * w3.x; acc[i][1] += ai.w * w3.y; acc[i][2] += ai.w * w3.z; acc[i][3] += ai.w * w3.w;
        GIN_STEP(a0, 0) GIN_STEP(a1, 1) GIN_STEP(a2, 2) GIN_STEP(a3, 3)
#undef GIN_STEP
    }
#pragma unroll
    for (int i = 0; i < 4; ++i) {
        int n = base + n0 + i;
        if (n < n_nodes) {
            float r0 = RELU ? fmaxf(acc[i][0], 0.f) : acc[i][0];
            float r1 = RELU ? fmaxf(acc[i][1], 0.f) : acc[i][1];
            float r2 = RELU ? fmaxf(acc[i][2], 0.f) : acc[i][2];
            float r3 = RELU ? fmaxf(acc[i][3], 0.f) : acc[i][3];
            if (BF16_OUT) {
                ushort4 o;
                o.x = f2bf(r0); o.y = f2bf(r1); o.z = f2bf(r2); o.w = f2bf(r3);
                *(ushort4*)&((u16*)out_v)[(size_t)n * 64 + j0] = o;
            } else {
                float4 o = make_float4(r0, r1, r2, r3);
                *(float4*)&((float*)out_v)[(size_t)n * 64 + j0] = o;
            }
        }
    }
}

// ============================ final: log_softmax(in @ Wf + bf), IN=64, OUT=40 ============================

__global__ __launch_bounds__(256) void final_logsoftmax_kernel(const float* __restrict__ in,
                                                               const float* __restrict__ W,
                                                               const float* __restrict__ bias,
                                                               float* __restrict__ out, int n_nodes) {
    __shared__ float sW[64 * 40];
    __shared__ float sB[40];
    __shared__ float sIn[100][68];
    __shared__ float sLog[100][40];
    const int tid = threadIdx.x;
    for (int i = tid; i < 64 * 10; i += 256) ((float4*)sW)[i] = ((const float4*)W)[i];
    if (tid < 40) sB[tid] = bias[tid];
    const int base = blockIdx.x * 100;
    for (int i = tid; i < 100 * 16; i += 256) {
        int nl = i / 16, k4 = i % 16;
        int n = base + nl;
        float4 v = make_float4(0.f, 0.f, 0.f, 0.f);
        if (n < n_nodes) v = ((const float4*)in)[(size_t)n * 16 + k4];
        *(float4*)&sIn[nl][k4 * 4] = v;
    }
    __syncthreads();
    if (tid < 250) {
        const int tj = tid % 10, tn = tid / 10;
        const int j0 = tj * 4, n0 = tn * 4;
        float acc[4][4];
#pragma unroll
        for (int i = 0; i < 4; ++i)
#pragma unroll
            for (int j = 0; j < 4; ++j) acc[i][j] = sB[j0 + j];
        for (int k = 0; k < 64; k += 4) {
            float4 a0 = *(const float4*)&sIn[n0 + 0][k];
            float4 a1 = *(const float4*)&sIn[n0 + 1][k];
            float4 a2 = *(const float4*)&sIn[n0 + 2][k];
            float4 a3 = *(const float4*)&sIn[n0 + 3][k];
            float4 w0 = *(const float4*)&sW[(k + 0) * 40 + j0];
            float4 w1 = *(const float4*)&sW[(k + 1) * 40 + j0];
            float4 w2 = *(const float4*)&sW[(k + 2) * 40 + j0];
            float4 w3 = *(const float4*)&sW[(k + 3) * 40 + j0];
#define GIN_STEP(ai, i)                                                                               \
            acc[i][0] += ai.x * w0.x; acc[i][1] += ai.x * w0.y; acc[i][2] += ai.x * w0.z; acc[i][3] += ai.x * w0.w; \
            acc[i][0] += ai.y * w1.x; acc[i][1] += ai.y * w1.y; acc[i][2] += ai.y * w1.z; acc[i][3] += ai.y * w1.w; \
            acc[i][0] += ai.z * w2.x; acc[i][1] += ai.z * w2.y; acc[i][2] += ai.z * w2.z; acc[i][3] += ai.z * w2.w; \
            acc[i][0] += ai.w * w3.x; acc[i][1] += ai.w * w3.y; acc[i][2] += ai.w * w3.z; acc[i][3] += ai.w * w3.w;
            GIN_STEP(a0, 0) GIN_STEP(a1, 1) GIN_STEP(a2, 2) GIN_STEP(a3, 3)
#undef GIN_STEP
        }
#pragma unroll
        for (int i = 0; i < 4; ++i)
            *(float4*)&sLog[n0 + i][j0] = make_float4(acc[i][0], acc[i][1], acc[i][2], acc[i][3]);
    }
    __syncthreads();
    for (int nl = tid; nl < 100; nl += 256) {
        int n = base + nl;
        if (n >= n_nodes) continue;
        float m = -1e30f;
        for (int j = 0; j < 40; ++j) m = fmaxf(m, sLog[nl][j]);
        float s = 0.f;
        for (int j = 0; j < 40; ++j) s += expf(sLog[nl][j] - m);
        float lse = m + logf(s);
        for (int j = 0; j < 40; j += 4) {
            float4 o;
            o.x = sLog[nl][j + 0] - lse;
            o.y = sLog[nl][j + 1] - lse;
            o.z = sLog[nl][j + 2] - lse;
            o.w = sLog[nl][j + 3] - lse;
            *(float4*)&out[(size_t)n * 40 + j] = o;
        }
    }
}

// ============================ launch ============================

extern "C" void kernel_launch(void* const* d_in, const int* in_sizes, int n_in,
                              void* d_out, int out_size, void* d_ws, size_t ws_size,
                              hipStream_t stream) {
    const float* x  = (const float*)d_in[0];
    const int*   ei = (const int*)d_in[1];
    const float* W1 = (const float*)d_in[2];
    const float* b1 = (const float*)d_in[3];
    const float* W2 = (const float*)d_in[4];
    const float* b2 = (const float*)d_in[5];
    const float* W3 = (const float*)d_in[6];
    const float* b3 = (const float*)d_in[7];
    const float* W4 = (const float*)d_in[8];
    const float* b4 = (const float*)d_in[9];
    const float* Wf = (const float*)d_in[10];
    const float* bf = (const float*)d_in[11];
    float* outp = (float*)d_out;

    const int N = N_NODES_C, E = N_EDGES_C;
    const int* srcp = ei;
    const int* dstp = ei + E;

    // workspace layout (~90.6 MB)
    char* ws = (char*)d_ws;
    int*          offs  = (int*)(ws);                    // N+1 ints        -> 400128
    int*          boffs = (int*)(ws + 400128);           // NB+1 ints       -> 404352
    int*          bsums = (int*)(ws + 404352);           // 256 ints        -> 405376
    int*          cnt   = (int*)(ws + 405376);           // NB*NBLK ints    -> 1018624
    unsigned int* stage = (unsigned int*)(ws + 1018624); // E u32           -> 13818624
    int*          srcs  = (int*)(ws + 13818624);         // E ints          -> 26618624
    u16*          Ybf   = (u16*)(ws + 26618624);         // N*64 bf16       -> 39418624
    float*        F2    = (float*)(ws + 39418624);       // N*64 f32        -> 65018624
    float*        F3    = (float*)(ws + 65018624);       // N*64 f32        -> 90618624

    // ---- atomic-free bucketed CSR build ----
    passA_hist_kernel<<<NBLK, 256, 0, stream>>>(dstp, cnt, E);
    const int n_scan = NB * NBLK;
    const int nblk_scan = (n_scan + 1023) / 1024;
    scan_chunks_kernel<<<nblk_scan, 256, 0, stream>>>(cnt, n_scan, bsums);
    scan_sums_kernel<<<1, 256, 0, stream>>>(bsums, nblk_scan);
    scan_add_kernel<<<nblk_scan, 256, 0, stream>>>(cnt, n_scan, bsums);
    boffs_kernel<<<1, 1024, 0, stream>>>(cnt, boffs, offs);
    passB_sort_kernel<<<NBLK, 256, 0, stream>>>(srcp, dstp, cnt, stage, E);
    bucket_finalize_kernel<<<NB, 256, 0, stream>>>(stage, boffs, offs, srcs);

    const int mlp_grid = (N + 63) / 64;
    const int gat_grid = (N + 3) / 4;

    // ---- conv1 via linearity: y = bf16(x@W1); h1 = relu(y_n + sum y_src + b1); c1r = relu(h1@W2+b2) ----
    mlp_layer_kernel<128, false, false, true><<<mlp_grid, 256, 0, stream>>>(x, W1, nullptr, Ybf, N);
    gather64v_kernel<<<gat_grid, 256, 0, stream>>>(Ybf, offs, srcs, b1, F2, N);
    mlp_layer_kernel<64, true, true, false><<<mlp_grid, 256, 0, stream>>>(F2, W2, b2, F3, N);

    // ---- conv2 via linearity: u = bf16(c1r@W3); h3 = relu(u_n + sum u_src + b3); c2r = relu(h3@W4+b4) ----
    mlp_layer_kernel<64, false, false, true><<<mlp_grid, 256, 0, stream>>>(F3, W3, nullptr, Ybf, N);
    gather64v_kernel<<<gat_grid, 256, 0, stream>>>(Ybf, offs, srcs, b3, F2, N);
    mlp_layer_kernel<64, true, true, false><<<mlp_grid, 256, 0, stream>>>(F2, W4, b4, F3, N);

    // ---- final fc + log_softmax ----
    final_logsoftmax_kernel<<<(N + 99) / 100, 256, 0, stream>>>(F3, Wf, bf, outp, N);
}

// Round 8
// 335.029 us; speedup vs baseline: 3.3565x; 1.0268x over previous
//
#include <hip/hip_runtime.h>
#include <math.h>

#define N_NODES_C 100000
#define N_EDGES_C 3200000
#define NB 782        // ceil(100000 / 128) buckets of 128 nodes
#define BNODES 128
#define LDS_CAP 6144  // per-bucket LDS staging capacity (mean ~4092, +32 sigma)
#define CHUNK 16384   // edges per partition block
#define NBLK 196      // ceil(N_EDGES_C / CHUNK)

typedef unsigned short u16;

__device__ __forceinline__ float bf2f(u16 u) {
    unsigned int t = ((unsigned int)u) << 16;
    return __uint_as_float(t);
}
__device__ __forceinline__ u16 f2bf(float f) {  // round-to-nearest-even
    unsigned int x = __float_as_uint(f);
    x += 0x7fffu + ((x >> 16) & 1u);
    return (u16)(x >> 16);
}

// ============================ atomic-free bucketed partition ============================

__global__ __launch_bounds__(256) void passA_hist_kernel(const int* __restrict__ dst,
                                                         int* __restrict__ cnt, int n_edges) {
    __shared__ int h[NB];
    for (int i = threadIdx.x; i < NB; i += 256) h[i] = 0;
    __syncthreads();
    const int blk = blockIdx.x;
    const int end = min((blk + 1) * CHUNK, n_edges);
    for (int e = blk * CHUNK + threadIdx.x; e < end; e += 256)
        atomicAdd(&h[dst[e] >> 7], 1);
    __syncthreads();
    for (int i = threadIdx.x; i < NB; i += 256) cnt[i * NBLK + blk] = h[i];
}

__global__ __launch_bounds__(256) void scan_chunks_kernel(int* __restrict__ a, int n, int* __restrict__ bsums) {
    __shared__ int s[256];
    const int tid = threadIdx.x;
    int base = blockIdx.x * 1024 + tid * 4;
    int v[4];
#pragma unroll
    for (int i = 0; i < 4; ++i) v[i] = (base + i < n) ? a[base + i] : 0;
    int tsum = v[0] + v[1] + v[2] + v[3];
    s[tid] = tsum;
    __syncthreads();
    for (int off = 1; off < 256; off <<= 1) {
        int t = (tid >= off) ? s[tid - off] : 0;
        __syncthreads();
        s[tid] += t;
        __syncthreads();
    }
    int run = s[tid] - tsum;
#pragma unroll
    for (int i = 0; i < 4; ++i) {
        run += v[i];
        if (base + i < n) a[base + i] = run;
    }
    if (tid == 255) bsums[blockIdx.x] = s[255];
}

__global__ __launch_bounds__(256) void scan_sums_kernel(int* __restrict__ bsums, int nb) {
    __shared__ int s[256];
    const int tid = threadIdx.x;
    int v = (tid < nb) ? bsums[tid] : 0;
    s[tid] = v;
    __syncthreads();
    for (int off = 1; off < 256; off <<= 1) {
        int t = (tid >= off) ? s[tid - off] : 0;
        __syncthreads();
        s[tid] += t;
        __syncthreads();
    }
    if (tid < nb) bsums[tid] = s[tid] - v;
}

__global__ __launch_bounds__(256) void scan_add_kernel(int* __restrict__ a, int n, const int* __restrict__ bsums) {
    int base = blockIdx.x * 1024 + threadIdx.x * 4;
    int add = bsums[blockIdx.x];
#pragma unroll
    for (int i = 0; i < 4; ++i)
        if (base + i < n) a[base + i] += add;
}

__global__ __launch_bounds__(1024) void boffs_kernel(const int* __restrict__ incl,
                                                     int* __restrict__ boffs,
                                                     int* __restrict__ offs) {
    const int b = threadIdx.x;
    if (b < NB) boffs[b] = b ? incl[b * NBLK - 1] : 0;
    if (b == 0) {
        int total = incl[NB * NBLK - 1];
        boffs[NB] = total;
        offs[N_NODES_C] = total;
    }
}

// pass B (LDS sort): block-local counting sort by bucket, then burst-write each run
__global__ __launch_bounds__(256) void passB_sort_kernel(const int* __restrict__ src,
                                                         const int* __restrict__ dst,
                                                         const int* __restrict__ incl,
                                                         unsigned int* __restrict__ stage,
                                                         int n_edges) {
    __shared__ unsigned int sdst[CHUNK];    // 64 KB
    __shared__ unsigned int spack[CHUNK];   // 64 KB
    __shared__ int hist[NB];
    __shared__ int lcur[NB];
    __shared__ int tsum[256];
    const int blk = blockIdx.x, tid = threadIdx.x;
    const int e0 = blk * CHUNK;
    const int cntE = min(CHUNK, n_edges - e0);

    for (int b = tid; b < NB; b += 256) hist[b] = 0;
    __syncthreads();

    if (cntE == CHUNK) {
        for (int i = tid * 4; i < CHUNK; i += 1024) {
            int4 d4 = *(const int4*)&dst[e0 + i];
            sdst[i + 0] = (unsigned)d4.x; sdst[i + 1] = (unsigned)d4.y;
            sdst[i + 2] = (unsigned)d4.z; sdst[i + 3] = (unsigned)d4.w;
            atomicAdd(&hist[d4.x >> 7], 1); atomicAdd(&hist[d4.y >> 7], 1);
            atomicAdd(&hist[d4.z >> 7], 1); atomicAdd(&hist[d4.w >> 7], 1);
        }
    } else {
        for (int i = tid; i < cntE; i += 256) {
            int d = dst[e0 + i];
            sdst[i] = (unsigned)d;
            atomicAdd(&hist[d >> 7], 1);
        }
    }
    __syncthreads();

    {
        int loc[4];
        const int bi = tid * 4;
        int s = 0;
#pragma unroll
        for (int k = 0; k < 4; ++k) {
            int idx = bi + k;
            loc[k] = (idx < NB) ? hist[idx] : 0;
            s += loc[k];
        }
        tsum[tid] = s;
        __syncthreads();
        for (int off = 1; off < 256; off <<= 1) {
            int t = (tid >= off) ? tsum[tid - off] : 0;
            __syncthreads();
            tsum[tid] += t;
            __syncthreads();
        }
        int run = tsum[tid] - s;
#pragma unroll
        for (int k = 0; k < 4; ++k) {
            int idx = bi + k;
            if (idx < NB) {
                int h = loc[k];
                hist[idx] = run;
                lcur[idx] = run;
                run += h;
            }
        }
    }
    __syncthreads();

    if (cntE == CHUNK) {
        for (int i = tid * 4; i < CHUNK; i += 1024) {
            int4 s4 = *(const int4*)&src[e0 + i];
            unsigned int d; int p;
            d = sdst[i + 0]; p = atomicAdd(&lcur[d >> 7], 1); spack[p] = (unsigned)s4.x | ((d & 127u) << 17);
            d = sdst[i + 1]; p = atomicAdd(&lcur[d >> 7], 1); spack[p] = (unsigned)s4.y | ((d & 127u) << 17);
            d = sdst[i + 2]; p = atomicAdd(&lcur[d >> 7], 1); spack[p] = (unsigned)s4.z | ((d & 127u) << 17);
            d = sdst[i + 3]; p = atomicAdd(&lcur[d >> 7], 1); spack[p] = (unsigned)s4.w | ((d & 127u) << 17);
        }
    } else {
        for (int i = tid; i < cntE; i += 256) {
            unsigned int d = sdst[i];
            int p = atomicAdd(&lcur[d >> 7], 1);
            spack[p] = (unsigned)src[e0 + i] | ((d & 127u) << 17);
        }
    }
    __syncthreads();

    for (int b = tid; b < NB; b += 256) {
        int l0 = hist[b];
        int l1 = (b + 1 < NB) ? hist[b + 1] : cntE;
        int idx = b * NBLK + blk;
        int g0 = idx ? incl[idx - 1] : 0;
        for (int j = l0; j < l1; ++j) stage[g0 + (j - l0)] = spack[j];
    }
}

__global__ __launch_bounds__(256) void bucket_finalize_kernel(const unsigned int* __restrict__ stage,
                                                              const int* __restrict__ boffs,
                                                              int* __restrict__ offs,
                                                              int* __restrict__ srcs) {
    __shared__ int hist[BNODES];
    __shared__ int excl[BNODES];
    __shared__ int curs[BNODES];
    __shared__ int sbuf[LDS_CAP];
    const int b = blockIdx.x, tid = threadIdx.x;
    const int base = boffs[b];
    const int count = boffs[b + 1] - base;
    const int n0 = b * BNODES;
    for (int i = tid; i < BNODES; i += 256) hist[i] = 0;
    __syncthreads();
    for (int i = tid; i < count; i += 256) {
        unsigned int w = stage[base + i];
        atomicAdd(&hist[w >> 17], 1);
    }
    __syncthreads();
    if (tid < BNODES) excl[tid] = hist[tid];
    __syncthreads();
    for (int off = 1; off < BNODES; off <<= 1) {
        int t = 0;
        if (tid < BNODES && tid >= off) t = excl[tid - off];
        __syncthreads();
        if (tid < BNODES) excl[tid] += t;
        __syncthreads();
    }
    if (tid < BNODES) {
        int ex = excl[tid] - hist[tid];
        int n = n0 + tid;
        if (n < N_NODES_C) offs[n] = base + ex;
        curs[tid] = ex;
    }
    __syncthreads();
    if (count <= LDS_CAP) {
        for (int i = tid; i < count; i += 256) {
            unsigned int w = stage[base + i];
            int p = atomicAdd(&curs[w >> 17], 1);
            sbuf[p] = (int)(w & 0x1FFFFu);
        }
        __syncthreads();
        for (int i = tid; i < count; i += 256) srcs[base + i] = sbuf[i];
    } else {
        for (int i = tid; i < count; i += 256) {
            unsigned int w = stage[base + i];
            int p = atomicAdd(&curs[w >> 17], 1);
            srcs[base + p] = (int)(w & 0x1FFFFu);
        }
    }
}

// ====== gather64v (bf16 feats): 16 lanes/row, 4 row-slots/wave, 16-row unroll ======

__global__ __launch_bounds__(256) void gather64v_kernel(const u16* __restrict__ feat,
                                                        const int* __restrict__ offs,
                                                        const int* __restrict__ srcs,
                                                        const float* __restrict__ bias,
                                                        float* __restrict__ out, int n_nodes) {
    const int wave = threadIdx.x >> 6;
    const int lane = threadIdx.x & 63;
    const int grp  = lane >> 4;
    const int cl   = lane & 15;
    const int n = blockIdx.x * 4 + wave;
    if (n >= n_nodes) return;

    float a0 = 0.f, a1 = 0.f, a2 = 0.f, a3 = 0.f;
    if (grp == 0) {
        ushort4 v = *(const ushort4*)&feat[(size_t)n * 64 + cl * 4];
        a0 = bf2f(v.x); a1 = bf2f(v.y); a2 = bf2f(v.z); a3 = bf2f(v.w);
    }
    const int s0 = offs[n], s1 = offs[n + 1];
    int i = s0;
    for (; i + 16 <= s1; i += 16) {  // 16 rows/iter: 4 independent feat loads per lane
        int r0 = srcs[i + grp];
        int r1 = srcs[i + 4 + grp];
        int r2 = srcs[i + 8 + grp];
        int r3 = srcs[i + 12 + grp];
        ushort4 v0 = *(const ushort4*)&feat[(size_t)r0 * 64 + cl * 4];
        ushort4 v1 = *(const ushort4*)&feat[(size_t)r1 * 64 + cl * 4];
        ushort4 v2 = *(const ushort4*)&feat[(size_t)r2 * 64 + cl * 4];
        ushort4 v3 = *(const ushort4*)&feat[(size_t)r3 * 64 + cl * 4];
        a0 += bf2f(v0.x); a1 += bf2f(v0.y); a2 += bf2f(v0.z); a3 += bf2f(v0.w);
        a0 += bf2f(v1.x); a1 += bf2f(v1.y); a2 += bf2f(v1.z); a3 += bf2f(v1.w);
        a0 += bf2f(v2.x); a1 += bf2f(v2.y); a2 += bf2f(v2.z); a3 += bf2f(v2.w);
        a0 += bf2f(v3.x); a1 += bf2f(v3.y); a2 += bf2f(v3.z); a3 += bf2f(v3.w);
    }
    for (; i + 4 <= s1; i += 4) {
        int r = srcs[i + grp];
        ushort4 v = *(const ushort4*)&feat[(size_t)r * 64 + cl * 4];
        a0 += bf2f(v.x); a1 += bf2f(v.y); a2 += bf2f(v.z); a3 += bf2f(v.w);
    }
    if (i + grp < s1) {
        int r = srcs[i + grp];
        ushort4 v = *(const ushort4*)&feat[(size_t)r * 64 + cl * 4];
        a0 += bf2f(v.x); a1 += bf2f(v.y); a2 += bf2f(v.z); a3 += bf2f(v.w);
    }
    a0 += __shfl_xor(a0, 16); a1 += __shfl_xor(a1, 16);
    a2 += __shfl_xor(a2, 16); a3 += __shfl_xor(a3, 16);
    a0 += __shfl_xor(a0, 32); a1 += __shfl_xor(a1, 32);
    a2 += __shfl_xor(a2, 32); a3 += __shfl_xor(a3, 32);
    if (lane < 16) {
        float4 b = *(const float4*)&bias[cl * 4];
        float4 o;
        o.x = fmaxf(a0 + b.x, 0.f);
        o.y = fmaxf(a1 + b.y, 0.f);
        o.z = fmaxf(a2 + b.z, 0.f);
        o.w = fmaxf(a3 + b.w, 0.f);
        *(float4*)&out[(size_t)n * 64 + cl * 4] = o;
    }
}

// ============== dense: out = [relu](in @ W [+ b]), OUT=64; optional bf16 output ==============

template <int IN_DIM, bool RELU, bool HAS_BIAS, bool BF16_OUT>
__global__ __launch_bounds__(256) void mlp_layer_kernel(const float* __restrict__ in,
                                                        const float* __restrict__ W,
                                                        const float* __restrict__ bias,
                                                        void* __restrict__ out_v, int n_nodes) {
    __shared__ float sW[IN_DIM * 64];
    __shared__ float sB[64];
    __shared__ float sIn[64][IN_DIM + 4];
    const int tid = threadIdx.x;
    for (int i = tid; i < IN_DIM * 16; i += 256) ((float4*)sW)[i] = ((const float4*)W)[i];
    if (HAS_BIAS) {
        if (tid < 64) sB[tid] = bias[tid];
    }
    const int base = blockIdx.x * 64;
    for (int i = tid; i < 16 * IN_DIM; i += 256) {
        int nl = i / (IN_DIM / 4);
        int k4 = i % (IN_DIM / 4);
        int n = base + nl;
        float4 v = make_float4(0.f, 0.f, 0.f, 0.f);
        if (n < n_nodes) v = ((const float4*)in)[(size_t)n * (IN_DIM / 4) + k4];
        *(float4*)&sIn[nl][k4 * 4] = v;
    }
    __syncthreads();
    const int tj = tid & 15, tn = tid >> 4;
    const int j0 = tj * 4, n0 = tn * 4;
    float acc[4][4];
#pragma unroll
    for (int i = 0; i < 4; ++i)
#pragma unroll
        for (int j = 0; j < 4; ++j) acc[i][j] = HAS_BIAS ? sB[j0 + j] : 0.f;
    for (int k = 0; k < IN_DIM; k += 4) {
        float4 a0 = *(const float4*)&sIn[n0 + 0][k];
        float4 a1 = *(const float4*)&sIn[n0 + 1][k];
        float4 a2 = *(const float4*)&sIn[n0 + 2][k];
        float4 a3 = *(const float4*)&sIn[n0 + 3][k];
        float4 w0 = *(const float4*)&sW[(k + 0) * 64 + j0];
        float4 w1 = *(const float4*)&sW[(k + 1) * 64 + j0];
        float4 w2 = *(const float4*)&sW[(k + 2) * 64 + j0];
        float4 w3 = *(const float4*)&sW[(k + 3) * 64 + j0];
#define GIN_STEP(ai, i)                                                                               \
        acc[i][0] += ai.x * w0.x; acc[i][1] += ai.x * w0.y; acc[i][2] += ai.x * w0.z; acc[i][3] += ai.x * w0.w; \
        acc[i][0] += ai.y * w1.x; acc[i][1] += ai.y * w1.y; acc[i][2] += ai.y * w1.z; acc[i][3] += ai.y * w1.w; \
        acc[i][0] += ai.z * w2.x; acc[i][1] += ai.z * w2.y; acc[i][2] += ai.z * w2.z; acc[i][3] += ai.z * w2.w; \
        acc[i][0] += ai.w * w3.x; acc[i][1] += ai.w * w3.y; acc[i][2] += ai.w * w3.z; acc[i][3] += ai.w * w3.w;
        GIN_STEP(a0, 0) GIN_STEP(a1, 1) GIN_STEP(a2, 2) GIN_STEP(a3, 3)
#undef GIN_STEP
    }
#pragma unroll
    for (int i = 0; i < 4; ++i) {
        int n = base + n0 + i;
        if (n < n_nodes) {
            float r0 = RELU ? fmaxf(acc[i][0], 0.f) : acc[i][0];
            float r1 = RELU ? fmaxf(acc[i][1], 0.f) : acc[i][1];
            float r2 = RELU ? fmaxf(acc[i][2], 0.f) : acc[i][2];
            float r3 = RELU ? fmaxf(acc[i][3], 0.f) : acc[i][3];
            if (BF16_OUT) {
                ushort4 o;
                o.x = f2bf(r0); o.y = f2bf(r1); o.z = f2bf(r2); o.w = f2bf(r3);
                *(ushort4*)&((u16*)out_v)[(size_t)n * 64 + j0] = o;
            } else {
                float4 o = make_float4(r0, r1, r2, r3);
                *(float4*)&((float*)out_v)[(size_t)n * 64 + j0] = o;
            }
        }
    }
}

// ====== fused: T = relu(in@W2 + b2); out_bf16 = T @ W3   (both 64x64, T in LDS) ======

__global__ __launch_bounds__(256) void fused_w2w3_kernel(const float* __restrict__ in,
                                                         const float* __restrict__ W2,
                                                         const float* __restrict__ b2,
                                                         const float* __restrict__ W3,
                                                         u16* __restrict__ out, int n_nodes) {
    __shared__ float sW2[64 * 64];
    __shared__ float sW3[64 * 64];
    __shared__ float sB[64];
    __shared__ float sIn[64][68];
    __shared__ float sT[64][68];
    const int tid = threadIdx.x;
    for (int i = tid; i < 64 * 16; i += 256) {
        ((float4*)sW2)[i] = ((const float4*)W2)[i];
        ((float4*)sW3)[i] = ((const float4*)W3)[i];
    }
    if (tid < 64) sB[tid] = b2[tid];
    const int base = blockIdx.x * 64;
    for (int i = tid; i < 16 * 64; i += 256) {
        int nl = i / 16, k4 = i % 16;
        int n = base + nl;
        float4 v = make_float4(0.f, 0.f, 0.f, 0.f);
        if (n < n_nodes) v = ((const float4*)in)[(size_t)n * 16 + k4];
        *(float4*)&sIn[nl][k4 * 4] = v;
    }
    __syncthreads();
    const int tj = tid & 15, tn = tid >> 4;
    const int j0 = tj * 4, n0 = tn * 4;
    float acc[4][4];
#pragma unroll
    for (int i = 0; i < 4; ++i)
#pragma unroll
        for (int j = 0; j < 4; ++j) acc[i][j] = sB[j0 + j];
    for (int k = 0; k < 64; k += 4) {
        float4 a0 = *(const float4*)&sIn[n0 + 0][k];
        float4 a1 = *(const float4*)&sIn[n0 + 1][k];
        float4 a2 = *(const float4*)&sIn[n0 + 2][k];
        float4 a3 = *(const float4*)&sIn[n0 + 3][k];
        float4 w0 = *(const float4*)&sW2[(k + 0) * 64 + j0];
        float4 w1 = *(const float4*)&sW2[(k + 1) * 64 + j0];
        float4 w2 = *(const float4*)&sW2[(k + 2) * 64 + j0];
        float4 w3 = *(const float4*)&sW2[(k + 3) * 64 + j0];
#define GIN_STEP(ai, i)                                                                               \
        acc[i][0] += ai.x * w0.x; acc[i][1] += ai.x * w0.y; acc[i][2] += ai.x * w0.z; acc[i][3] += ai.x * w0.w; \
        acc[i][0] += ai.y * w1.x; acc[i][1] += ai.y * w1.y; acc[i][2] += ai.y * w1.z; acc[i][3] += ai.y * w1.w; \
        acc[i][0] += ai.z * w2.x; acc[i][1] += ai.z * w2.y; acc[i][2] += ai.z * w2.z; acc[i][3] += ai.z * w2.w; \
        acc[i][0] += ai.w * w3.x; acc[i][1] += ai.w * w3.y; acc[i][2] += ai.w * w3.z; acc[i][3] += ai.w * w3.w;
        GIN_STEP(a0, 0) GIN_STEP(a1, 1) GIN_STEP(a2, 2) GIN_STEP(a3, 3)
    }
#pragma unroll
    for (int i = 0; i < 4; ++i) {
        float4 t;
        t.x = fmaxf(acc[i][0], 0.f); t.y = fmaxf(acc[i][1], 0.f);
        t.z = fmaxf(acc[i][2], 0.f); t.w = fmaxf(acc[i][3], 0.f);
        *(float4*)&sT[n0 + i][j0] = t;
    }
    __syncthreads();
    // GEMM2: out = sT @ W3 (no bias, no relu), bf16 out
#pragma unroll
    for (int i = 0; i < 4; ++i)
#pragma unroll
        for (int j = 0; j < 4; ++j) acc[i][j] = 0.f;
    for (int k = 0; k < 64; k += 4) {
        float4 a0 = *(const float4*)&sT[n0 + 0][k];
        float4 a1 = *(const float4*)&sT[n0 + 1][k];
        float4 a2 = *(const float4*)&sT[n0 + 2][k];
        float4 a3 = *(const float4*)&sT[n0 + 3][k];
        float4 w0 = *(const float4*)&sW3[(k + 0) * 64 + j0];
        float4 w1 = *(const float4*)&sW3[(k + 1) * 64 + j0];
        float4 w2 = *(const float4*)&sW3[(k + 2) * 64 + j0];
        float4 w3 = *(const float4*)&sW3[(k + 3) * 64 + j0];
        GIN_STEP(a0, 0) GIN_STEP(a1, 1) GIN_STEP(a2, 2) GIN_STEP(a3, 3)
#undef GIN_STEP
    }
#pragma unroll
    for (int i = 0; i < 4; ++i) {
        int n = base + n0 + i;
        if (n < n_nodes) {
            ushort4 o;
            o.x = f2bf(acc[i][0]); o.y = f2bf(acc[i][1]);
            o.z = f2bf(acc[i][2]); o.w = f2bf(acc[i][3]);
            *(ushort4*)&out[(size_t)n * 64 + j0] = o;
        }
    }
}

// ====== fused final: T = relu(in@W4 + b4); logits = T@Wf + bf; out = log_softmax ======

__global__ __launch_bounds__(256) void fused_w4final_kernel(const float* __restrict__ in,
                                                            const float* __restrict__ W4,
                                                            const float* __restrict__ b4,
                                                            const float* __restrict__ Wf,
                                                            const float* __restrict__ bfin,
                                                            float* __restrict__ out, int n_nodes) {
    __shared__ float sW4[64 * 64];
    __shared__ float sWf[64 * 40];
    __shared__ float sB4[64];
    __shared__ float sBf[40];
    __shared__ float sIn[64][68];
    __shared__ float sT[64][68];
    __shared__ float sLog[64][40];
    const int tid = threadIdx.x;
    for (int i = tid; i < 64 * 16; i += 256) ((float4*)sW4)[i] = ((const float4*)W4)[i];
    for (int i = tid; i < 64 * 10; i += 256) ((float4*)sWf)[i] = ((const float4*)Wf)[i];
    if (tid < 64) sB4[tid] = b4[tid];
    if (tid < 40) sBf[tid] = bfin[tid];
    const int base = blockIdx.x * 64;
    for (int i = tid; i < 16 * 64; i += 256) {
        int nl = i / 16, k4 = i % 16;
        int n = base + nl;
        float4 v = make_float4(0.f, 0.f, 0.f, 0.f);
        if (n < n_nodes) v = ((const float4*)in)[(size_t)n * 16 + k4];
        *(float4*)&sIn[nl][k4 * 4] = v;
    }
    __syncthreads();
    {
        const int tj = tid & 15, tn = tid >> 4;
        const int j0 = tj * 4, n0 = tn * 4;
        float acc[4][4];
#pragma unroll
        for (int i = 0; i < 4; ++i)
#pragma unroll
            for (int j = 0; j < 4; ++j) acc[i][j] = sB4[j0 + j];
        for (int k = 0; k < 64; k += 4) {
            float4 a0 = *(const float4*)&sIn[n0 + 0][k];
            float4 a1 = *(const float4*)&sIn[n0 + 1][k];
            float4 a2 = *(const float4*)&sIn[n0 + 2][k];
            float4 a3 = *(const float4*)&sIn[n0 + 3][k];
            float4 w0 = *(const float4*)&sW4[(k + 0) * 64 + j0];
            float4 w1 = *(const float4*)&sW4[(k + 1) * 64 + j0];
            float4 w2 = *(const float4*)&sW4[(k + 2) * 64 + j0];
            float4 w3 = *(const float4*)&sW4[(k + 3) * 64 + j0];
#define GIN_STEP(ai, i)                                                                               \
            acc[i][0] += ai.x * w0.x; acc[i][1] += ai.x * w0.y; acc[i][2] += ai.x * w0.z; acc[i][3] += ai.x * w0.w; \
            acc[i][0] += ai.y * w1.x; acc[i][1] += ai.y * w1.y; acc[i][2] += ai.y * w1.z; acc[i][3] += ai.y * w1.w; \
            acc[i][0] += ai.z * w2.x; acc[i][1] += ai.z * w2.y; acc[i][2] += ai.z * w2.z; acc[i][3] += ai.z * w2.w; \
            acc[i][0] += ai.w * w3.x; acc[i][1] += ai.w * w3.y; acc[i][2] += ai.w * w3.z; acc[i][3] += ai.w * w3.w;
            GIN_STEP(a0, 0) GIN_STEP(a1, 1) GIN_STEP(a2, 2) GIN_STEP(a3, 3)
        }
#pragma unroll
        for (int i = 0; i < 4; ++i) {
            float4 t;
            t.x = fmaxf(acc[i][0], 0.f); t.y = fmaxf(acc[i][1], 0.f);
            t.z = fmaxf(acc[i][2], 0.f); t.w = fmaxf(acc[i][3], 0.f);
            *(float4*)&sT[n0 + i][j0] = t;
        }
    }
    __syncthreads();
    if (tid < 160) {  // GEMM2: 64 nodes x 40 outs
        const int tj = tid % 10, tn = tid / 10;
        const int j0 = tj * 4, n0 = tn * 4;
        float acc[4][4];
#pragma unroll
        for (int i = 0; i < 4; ++i)
#pragma unroll
            for (int j = 0; j < 4; ++j) acc[i][j] = sBf[j0 + j];
        for (int k = 0; k < 64; k += 4) {
            float4 a0 = *(const float4*)&sT[n0 + 0][k];
            float4 a1 = *(const float4*)&sT[n0 + 1][k];
            float4 a2 = *(const float4*)&sT[n0 + 2][k];
            float4 a3 = *(const float4*)&sT[n0 + 3][k];
            float4 w0 = *(const float4*)&sWf[(k + 0) * 40 + j0];
            float4 w1 = *(const float4*)&sWf[(k + 1) * 40 + j0];
            float4 w2 = *(const float4*)&sWf[(k + 2) * 40 + j0];
            float4 w3 = *(const float4*)&sWf[(k + 3) * 40 + j0];
            GIN_STEP(a0, 0) GIN_STEP(a1, 1) GIN_STEP(a2, 2) GIN_STEP(a3, 3)
#undef GIN_STEP
        }
#pragma unroll
        for (int i = 0; i < 4; ++i)
            *(float4*)&sLog[n0 + i][j0] = make_float4(acc[i][0], acc[i][1], acc[i][2], acc[i][3]);
    }
    __syncthreads();
    if (tid < 64) {
        const int nl = tid;
        const int n = base + nl;
        if (n < n_nodes) {
            float m = -1e30f;
            for (int j = 0; j < 40; ++j) m = fmaxf(m, sLog[nl][j]);
            float s = 0.f;
            for (int j = 0; j < 40; ++j) s += expf(sLog[nl][j] - m);
            float lse = m + logf(s);
            for (int j = 0; j < 40; j += 4) {
                float4 o;
                o.x = sLog[nl][j + 0] - lse;
                o.y = sLog[nl][j + 1] - lse;
                o.z = sLog[nl][j + 2] - lse;
                o.w = sLog[nl][j + 3] - lse;
                *(float4*)&out[(size_t)n * 40 + j] = o;
            }
        }
    }
}

// ============================ launch ============================

extern "C" void kernel_launch(void* const* d_in, const int* in_sizes, int n_in,
                              void* d_out, int out_size, void* d_ws, size_t ws_size,
                              hipStream_t stream) {
    const float* x  = (const float*)d_in[0];
    const int*   ei = (const int*)d_in[1];
    const float* W1 = (const float*)d_in[2];
    const float* b1 = (const float*)d_in[3];
    const float* W2 = (const float*)d_in[4];
    const float* b2 = (const float*)d_in[5];
    const float* W3 = (const float*)d_in[6];
    const float* b3 = (const float*)d_in[7];
    const float* W4 = (const float*)d_in[8];
    const float* b4 = (const float*)d_in[9];
    const float* Wf = (const float*)d_in[10];
    const float* bf = (const float*)d_in[11];
    float* outp = (float*)d_out;

    const int N = N_NODES_C, E = N_EDGES_C;
    const int* srcp = ei;
    const int* dstp = ei + E;

    // workspace layout (~65 MB)
    char* ws = (char*)d_ws;
    int*          offs  = (int*)(ws);                    // N+1 ints        -> 400128
    int*          boffs = (int*)(ws + 400128);           // NB+1 ints       -> 404352
    int*          bsums = (int*)(ws + 404352);           // 256 ints        -> 405376
    int*          cnt   = (int*)(ws + 405376);           // NB*NBLK ints    -> 1018624
    unsigned int* stage = (unsigned int*)(ws + 1018624); // E u32           -> 13818624
    int*          srcs  = (int*)(ws + 13818624);         // E ints          -> 26618624
    u16*          Ybf   = (u16*)(ws + 26618624);         // N*64 bf16       -> 39418624
    float*        F2    = (float*)(ws + 39418624);       // N*64 f32        -> 65018624

    // ---- atomic-free bucketed CSR build ----
    passA_hist_kernel<<<NBLK, 256, 0, stream>>>(dstp, cnt, E);
    const int n_scan = NB * NBLK;
    const int nblk_scan = (n_scan + 1023) / 1024;
    scan_chunks_kernel<<<nblk_scan, 256, 0, stream>>>(cnt, n_scan, bsums);
    scan_sums_kernel<<<1, 256, 0, stream>>>(bsums, nblk_scan);
    scan_add_kernel<<<nblk_scan, 256, 0, stream>>>(cnt, n_scan, bsums);
    boffs_kernel<<<1, 1024, 0, stream>>>(cnt, boffs, offs);
    passB_sort_kernel<<<NBLK, 256, 0, stream>>>(srcp, dstp, cnt, stage, E);
    bucket_finalize_kernel<<<NB, 256, 0, stream>>>(stage, boffs, offs, srcs);

    const int mlp_grid = (N + 63) / 64;
    const int gat_grid = (N + 3) / 4;

    // ---- conv1: y = bf16(x@W1); h1 = relu(y_n + sum y_src + b1); u = bf16(relu(h1@W2+b2)@W3) ----
    mlp_layer_kernel<128, false, false, true><<<mlp_grid, 256, 0, stream>>>(x, W1, nullptr, Ybf, N);
    gather64v_kernel<<<gat_grid, 256, 0, stream>>>(Ybf, offs, srcs, b1, F2, N);
    fused_w2w3_kernel<<<mlp_grid, 256, 0, stream>>>(F2, W2, b2, W3, Ybf, N);

    // ---- conv2: h3 = relu(u_n + sum u_src + b3); out = logsoftmax(relu(h3@W4+b4)@Wf + bf) ----
    gather64v_kernel<<<gat_grid, 256, 0, stream>>>(Ybf, offs, srcs, b3, F2, N);
    fused_w4final_kernel<<<mlp_grid, 256, 0, stream>>>(F2, W4, b4, Wf, bf, outp, N);
}